// Round 11
// baseline (460.299 us; speedup 1.0000x reference)
//
#include <hip/hip_runtime.h>

#define BATCH 2
#define SEQ 512
#define DMODEL 512
#define DINNER 1024
#define DSTATE 16
#define DTRANK 32
#define NBL (BATCH*SEQ)      // 1024
#define EPSV 1e-5f

typedef __attribute__((ext_vector_type(8))) short bf16x8;
typedef __attribute__((ext_vector_type(4))) float f32x4;

static __device__ __forceinline__ float sigmoidf_(float x) {
  return 1.0f / (1.0f + __expf(-x));
}
static __device__ __forceinline__ float softplusf_(float x) {
  return fmaxf(x, 0.0f) + log1pf(__expf(-fabsf(x)));
}
static __device__ __forceinline__ unsigned short f2bf(float x) {
  unsigned int u = __float_as_uint(x);
  unsigned int r = (u + 0x7FFFu + ((u >> 16) & 1u)) >> 16;
  return (unsigned short)r;
}

// ---------------- all-weight fp32 -> bf16 convert (segmented) ----------------
__global__ __launch_bounds__(256) void wconvert_kernel(
    const float* __restrict__ s0, const float* __restrict__ s1,
    const float* __restrict__ s2, const float* __restrict__ s3,
    const float* __restrict__ s4, const float* __restrict__ s5,
    unsigned short* __restrict__ d0, unsigned short* __restrict__ d1,
    unsigned short* __restrict__ d2, unsigned short* __restrict__ d3,
    unsigned short* __restrict__ d4, unsigned short* __restrict__ d5) {
  long i = (long)(blockIdx.x * 256 + threadIdx.x) * 8;
  const float* src; unsigned short* dst;
  if (i < 4194304)      { src = s0; dst = d0; }
  else if (i < 6291456) { src = s1; dst = d1; i -= 4194304; }
  else if (i < 6553600) { src = s2; dst = d2; i -= 6291456; }
  else if (i < 6815744) { src = s3; dst = d3; i -= 6553600; }
  else if (i < 6946816) { src = s4; dst = d4; i -= 6815744; }
  else                  { src = s5; dst = d5; i -= 6946816; }
  const float4 v0 = *(const float4*)&src[i];
  const float4 v1 = *(const float4*)&src[i + 4];
  bf16x8 o;
  o[0] = (short)f2bf(v0.x); o[1] = (short)f2bf(v0.y);
  o[2] = (short)f2bf(v0.z); o[3] = (short)f2bf(v0.w);
  o[4] = (short)f2bf(v1.x); o[5] = (short)f2bf(v1.y);
  o[6] = (short)f2bf(v1.z); o[7] = (short)f2bf(v1.w);
  *(bf16x8*)&dst[i] = o;
}

// ---------------- prep: xpwT transpose + Acomb B/C rows + zero pad ----------
// grid (32 e-tiles, 8 layer-dir)
__global__ __launch_bounds__(256) void prep_kernel(
    const unsigned short* __restrict__ xpwb_f, const unsigned short* __restrict__ xpwb_r,
    unsigned short* __restrict__ xpwT, unsigned short* __restrict__ Acomb) {
  __shared__ unsigned short tile[32][33];
  const int ld = blockIdx.y;
  const int layer = ld >> 1, dir = ld & 1;
  const unsigned short* xpwb = (dir ? xpwb_r : xpwb_f) + (long)layer * 64 * DINNER;
  unsigned short* xT = xpwT + (long)ld * DINNER * DTRANK;
  unsigned short* Ac = Acomb + (long)ld * 1152 * DINNER;
  const int e0 = blockIdx.x * 32;
  const int t = threadIdx.x;
  const int c = t & 31, rr = t >> 5;
  // transpose rows 0..31 (dt projection) -> xpwT[e][r]
  #pragma unroll
  for (int p = 0; p < 4; ++p)
    tile[p * 8 + rr][c] = xpwb[(long)(p * 8 + rr) * DINNER + e0 + c];
  __syncthreads();
  #pragma unroll
  for (int p = 0; p < 4; ++p)
    xT[(long)(e0 + p * 8 + rr) * DTRANK + c] = tile[c][p * 8 + rr];
  // copy B/C rows 32..63 -> Acomb rows 0..31
  #pragma unroll
  for (int p = 0; p < 4; ++p)
    Ac[(long)(p * 8 + rr) * DINNER + e0 + c] =
        xpwb[(long)(32 + p * 8 + rr) * DINNER + e0 + c];
  // zero pad rows 1056..1151 (3 rows per block)
  #pragma unroll
  for (int q = 0; q < 3; ++q) {
    unsigned short* zr = Ac + (long)(1056 + 3 * blockIdx.x + q) * DINNER;
    ((unsigned long long*)zr)[t] = 0ULL;
  }
}

#define LDK 40
#define LDK2 72

// ---------------- W_delta = dtw @ xpw_dt^T, K=32 single step ----------------
// grid (8 e-tiles, 8 d-tiles, 8 layer-dir). Out: Acomb rows 32+d, bf16.
__global__ __launch_bounds__(256) void wdelta_kernel(
    const unsigned short* __restrict__ dtwb_f, const unsigned short* __restrict__ dtwb_r,
    const unsigned short* __restrict__ xpwT, unsigned short* __restrict__ Acomb) {
  __shared__ unsigned short As[128 * LDK];
  __shared__ unsigned short Bs[128 * LDK];
  const int t = threadIdx.x;
  const int ld = blockIdx.z;
  const int layer = ld >> 1, dir = ld & 1;
  const unsigned short* A = (dir ? dtwb_r : dtwb_f) + (long)layer * DINNER * DTRANK;
  const unsigned short* B = xpwT + (long)ld * DINNER * DTRANK;
  unsigned short* Ac = Acomb + (long)ld * 1152 * DINNER;
  const int m0 = blockIdx.y * 128, n0 = blockIdx.x * 128;
  const int lane = t & 63;
  const int w = t >> 6;
  const int wr = (w >> 1) * 64, wc = (w & 1) * 64;
  const int fr = lane & 15;
  const int fq = lane >> 4;

  const int srow = t >> 1;
  const int sko = (t & 1) * 16;
  *(bf16x8*)&As[srow * LDK + sko] =
      *(const bf16x8*)&A[(long)(m0 + srow) * DTRANK + sko];
  *(bf16x8*)&As[srow * LDK + sko + 8] =
      *(const bf16x8*)&A[(long)(m0 + srow) * DTRANK + sko + 8];
  *(bf16x8*)&Bs[srow * LDK + sko] =
      *(const bf16x8*)&B[(long)(n0 + srow) * DTRANK + sko];
  *(bf16x8*)&Bs[srow * LDK + sko + 8] =
      *(const bf16x8*)&B[(long)(n0 + srow) * DTRANK + sko + 8];
  __syncthreads();

  bf16x8 af[4], bg[4];
  #pragma unroll
  for (int i = 0; i < 4; ++i) {
    af[i] = *(const bf16x8*)&As[(wr + i * 16 + fr) * LDK + fq * 8];
    bg[i] = *(const bf16x8*)&Bs[(wc + i * 16 + fr) * LDK + fq * 8];
  }
  #pragma unroll
  for (int i = 0; i < 4; ++i)
    #pragma unroll
    for (int j = 0; j < 4; ++j) {
      f32x4 z = {0.f, 0.f, 0.f, 0.f};
      const f32x4 a2 = __builtin_amdgcn_mfma_f32_16x16x32_bf16(af[i], bg[j], z, 0, 0, 0);
      const int m = m0 + wr + i * 16 + fq * 4;
      const int n = n0 + wc + j * 16 + fr;
      #pragma unroll
      for (int r2 = 0; r2 < 4; ++r2)
        Ac[(long)(32 + m + r2) * DINNER + n] = f2bf(a2[r2]);
    }
}

// ---------------- fused add + RMSNorm ----------------
__global__ __launch_bounds__(256) void addnorm_kernel(
    const float* __restrict__ hs, float* __restrict__ residual,
    const float* __restrict__ w, float* __restrict__ out,
    unsigned short* __restrict__ outb, int first) {
  const int row = blockIdx.x;
  const int t = threadIdx.x;
  const float* hp = hs + (long)row * DMODEL;
  float* rp = residual + (long)row * DMODEL;
  float r0 = hp[t], r1 = hp[t + 256];
  if (!first) { r0 += rp[t]; r1 += rp[t + 256]; }
  rp[t] = r0; rp[t + 256] = r1;
  float ss = r0 * r0 + r1 * r1;
  #pragma unroll
  for (int off = 32; off; off >>= 1) ss += __shfl_xor(ss, off, 64);
  __shared__ float sw[4];
  const int wid = t >> 6, lane = t & 63;
  if (lane == 0) sw[wid] = ss;
  __syncthreads();
  const float tot = sw[0] + sw[1] + sw[2] + sw[3];
  const float scale = rsqrtf(tot * (1.0f / (float)DMODEL) + EPSV);
  const float v0 = r0 * scale * w[t];
  const float v1 = r1 * scale * w[t + 256];
  if (out) {
    out[(long)row * DMODEL + t] = v0;
    out[(long)row * DMODEL + t + 256] = v1;
  }
  if (outb) {
    outb[(long)row * DMODEL + t] = f2bf(v0);
    outb[(long)row * DMODEL + t + 256] = f2bf(v1);
  }
}

// ---------------- in_proj GEMM: 128M x 64N, BK=64, reg-prefetch -------------
__global__ __launch_bounds__(256) void gemm_in_kernel(
    const unsigned short* __restrict__ A, const unsigned short* __restrict__ B,
    float* __restrict__ C) {
  __shared__ unsigned short As[128 * LDK2];
  __shared__ unsigned short Bs[64 * LDK2];
  const int t = threadIdx.x;
  const int m0 = blockIdx.y * 128, n0 = blockIdx.x * 64;
  const int lane = t & 63;
  const int w = t >> 6;
  const int wr = (w >> 1) * 64, wc = (w & 1) * 32;
  const int fr = lane & 15;
  const int fq = lane >> 4;
  const int K = DMODEL;

  f32x4 acc[4][2];
  #pragma unroll
  for (int i = 0; i < 4; ++i)
    #pragma unroll
    for (int j = 0; j < 2; ++j) {
      f32x4 z = {0.f, 0.f, 0.f, 0.f};
      acc[i][j] = z;
    }

  const int arow = t >> 1, ako = (t & 1) * 32;   // A: 128 x 64
  const int brow = t >> 2, bko = (t & 3) * 16;   // B: 64 x 64

  bf16x8 pa[4], pb[2];
  #define LOADG_IN(k0_) do {                                              \
    const unsigned short* ap = &A[(long)(m0 + arow) * K + (k0_) + ako];   \
    pa[0] = *(const bf16x8*)ap;        pa[1] = *(const bf16x8*)(ap + 8);  \
    pa[2] = *(const bf16x8*)(ap + 16); pa[3] = *(const bf16x8*)(ap + 24); \
    const unsigned short* bp = &B[(long)(n0 + brow) * K + (k0_) + bko];   \
    pb[0] = *(const bf16x8*)bp;        pb[1] = *(const bf16x8*)(bp + 8);  \
  } while (0)

  LOADG_IN(0);
  for (int k0 = 0; k0 < K; k0 += 64) {
    if (k0) __syncthreads();
    *(bf16x8*)&As[arow * LDK2 + ako]      = pa[0];
    *(bf16x8*)&As[arow * LDK2 + ako + 8]  = pa[1];
    *(bf16x8*)&As[arow * LDK2 + ako + 16] = pa[2];
    *(bf16x8*)&As[arow * LDK2 + ako + 24] = pa[3];
    *(bf16x8*)&Bs[brow * LDK2 + bko]      = pb[0];
    *(bf16x8*)&Bs[brow * LDK2 + bko + 8]  = pb[1];
    __syncthreads();
    if (k0 + 64 < K) LOADG_IN(k0 + 64);
    #pragma unroll
    for (int h = 0; h < 2; ++h) {
      bf16x8 af[4], bg[2];
      #pragma unroll
      for (int i = 0; i < 4; ++i)
        af[i] = *(const bf16x8*)&As[(wr + i * 16 + fr) * LDK2 + h * 32 + fq * 8];
      #pragma unroll
      for (int j = 0; j < 2; ++j)
        bg[j] = *(const bf16x8*)&Bs[(wc + j * 16 + fr) * LDK2 + h * 32 + fq * 8];
      #pragma unroll
      for (int i = 0; i < 4; ++i)
        #pragma unroll
        for (int j = 0; j < 2; ++j)
          acc[i][j] = __builtin_amdgcn_mfma_f32_16x16x32_bf16(
              af[i], bg[j], acc[i][j], 0, 0, 0);
    }
  }
  #undef LOADG_IN

  #pragma unroll
  for (int i = 0; i < 4; ++i)
    #pragma unroll
    for (int j = 0; j < 2; ++j)
      #pragma unroll
      for (int r2 = 0; r2 < 4; ++r2) {
        const int m = m0 + wr + i * 16 + fq * 4 + r2;
        const int n = n0 + wc + j * 16 + fr;
        C[(long)m * NBL + n] = acc[i][j][r2];
      }
}

// ---------------- conv+SiLU + transposed bf16 out (fused xct) ----------------
__global__ __launch_bounds__(256) void conv_silu_kernel(
    const float* __restrict__ xz,
    const float* __restrict__ cw_f, const float* __restrict__ cb_f,
    const float* __restrict__ cw_r, const float* __restrict__ cb_r,
    float* __restrict__ xconv_f, float* __restrict__ xconv_r,
    unsigned short* __restrict__ xcT) {
  __shared__ unsigned short tile[32][33];
  const int dir = blockIdx.z;
  const int n0 = blockIdx.x * 32, d0 = blockIdx.y * 32;
  const int b = n0 >> 9;
  const int l0 = n0 & (SEQ - 1);
  const float* cw = dir ? cw_r : cw_f;
  const float* cb = dir ? cb_r : cb_f;
  float* xconv = dir ? xconv_r : xconv_f;
  unsigned short* dst = xcT + (long)dir * DINNER * NBL;
  const int t = threadIdx.x;
  const int c = t & 31, rr = t >> 5;
  #pragma unroll
  for (int p = 0; p < 4; ++p) {
    const int d = d0 + p * 8 + rr;
    const int l = l0 + c;
    const float* xi = xz + (long)d * NBL + b * SEQ;
    float sum = cb[d];
    #pragma unroll
    for (int k = 0; k < 4; ++k) {
      const int tt = l - 3 + k;
      if (tt >= 0) {
        const int src = dir ? (SEQ - 1 - tt) : tt;
        sum += cw[d * 4 + k] * xi[src];
      }
    }
    const float v = sum * sigmoidf_(sum);
    xconv[(long)d * NBL + n0 + c] = v;
    tile[p * 8 + rr][c] = f2bf(v);
  }
  __syncthreads();
  #pragma unroll
  for (int p = 0; p < 4; ++p) {
    const int n = n0 + p * 8 + rr;
    dst[(long)n * DINNER + d0 + c] = tile[c][p * 8 + rr];
  }
}

// ---------------- fused projection GEMM: Acomb(1152,1024) @ xcT^T -----------
// 128x128 tile, BK=64 reg-prefetch, grid (8 n, 9 m, 2 dir).
// rows 0..31 -> xbc fp32 slot-major; rows 32..1055 -> delta = softplus(+dtb).
__global__ __launch_bounds__(256) void fusedproj_kernel(
    const unsigned short* __restrict__ Acomb, const unsigned short* __restrict__ xcT,
    const float* __restrict__ dtb_f, const float* __restrict__ dtb_r,
    float* __restrict__ xbc_f, float* __restrict__ xbc_r,
    float* __restrict__ delta_f, float* __restrict__ delta_r, int layer) {
  __shared__ unsigned short As[128 * LDK2];
  __shared__ unsigned short Bs[128 * LDK2];
  const int t = threadIdx.x;
  const int dir = blockIdx.z;
  const int ld = layer * 2 + dir;
  const unsigned short* A = Acomb + (long)ld * 1152 * DINNER;
  const unsigned short* B = xcT + (long)dir * DINNER * NBL;
  const float* dtb = (dir ? dtb_r : dtb_f) + (long)layer * DINNER;
  float* xbc = dir ? xbc_r : xbc_f;
  float* dl = dir ? delta_r : delta_f;
  const int m0 = blockIdx.y * 128, n0 = blockIdx.x * 128;
  const int lane = t & 63;
  const int w = t >> 6;
  const int wr = (w >> 1) * 64, wc = (w & 1) * 64;
  const int fr = lane & 15;
  const int fq = lane >> 4;
  const int K = DINNER;

  f32x4 acc[4][4];
  #pragma unroll
  for (int i = 0; i < 4; ++i)
    #pragma unroll
    for (int j = 0; j < 4; ++j) {
      f32x4 z = {0.f, 0.f, 0.f, 0.f};
      acc[i][j] = z;
    }

  const int srow = t >> 1, sko = (t & 1) * 32;

  bf16x8 pa[4], pb[4];
  #define LOADG_FP(k0_) do {                                               \
    const unsigned short* ap = &A[(long)(m0 + srow) * K + (k0_) + sko];    \
    pa[0] = *(const bf16x8*)ap;        pa[1] = *(const bf16x8*)(ap + 8);   \
    pa[2] = *(const bf16x8*)(ap + 16); pa[3] = *(const bf16x8*)(ap + 24);  \
    const unsigned short* bp = &B[(long)(n0 + srow) * K + (k0_) + sko];    \
    pb[0] = *(const bf16x8*)bp;        pb[1] = *(const bf16x8*)(bp + 8);   \
    pb[2] = *(const bf16x8*)(bp + 16); pb[3] = *(const bf16x8*)(bp + 24);  \
  } while (0)

  LOADG_FP(0);
  for (int k0 = 0; k0 < K; k0 += 64) {
    if (k0) __syncthreads();
    *(bf16x8*)&As[srow * LDK2 + sko]      = pa[0];
    *(bf16x8*)&As[srow * LDK2 + sko + 8]  = pa[1];
    *(bf16x8*)&As[srow * LDK2 + sko + 16] = pa[2];
    *(bf16x8*)&As[srow * LDK2 + sko + 24] = pa[3];
    *(bf16x8*)&Bs[srow * LDK2 + sko]      = pb[0];
    *(bf16x8*)&Bs[srow * LDK2 + sko + 8]  = pb[1];
    *(bf16x8*)&Bs[srow * LDK2 + sko + 16] = pb[2];
    *(bf16x8*)&Bs[srow * LDK2 + sko + 24] = pb[3];
    __syncthreads();
    if (k0 + 64 < K) LOADG_FP(k0 + 64);
    #pragma unroll
    for (int h = 0; h < 2; ++h) {
      bf16x8 af[4], bg[4];
      #pragma unroll
      for (int i = 0; i < 4; ++i) {
        af[i] = *(const bf16x8*)&As[(wr + i * 16 + fr) * LDK2 + h * 32 + fq * 8];
        bg[i] = *(const bf16x8*)&Bs[(wc + i * 16 + fr) * LDK2 + h * 32 + fq * 8];
      }
      #pragma unroll
      for (int i = 0; i < 4; ++i)
        #pragma unroll
        for (int j = 0; j < 4; ++j)
          acc[i][j] = __builtin_amdgcn_mfma_f32_16x16x32_bf16(
              af[i], bg[j], acc[i][j], 0, 0, 0);
    }
  }
  #undef LOADG_FP

  #pragma unroll
  for (int i = 0; i < 4; ++i)
    #pragma unroll
    for (int j = 0; j < 4; ++j)
      #pragma unroll
      for (int r2 = 0; r2 < 4; ++r2) {
        const int m = m0 + wr + i * 16 + fq * 4 + r2;
        const int n = n0 + wc + j * 16 + fr;
        const float v = acc[i][j][r2];
        if (m < 32) {
          xbc[(long)m * NBL + n] = v;
        } else if (m < 1056) {
          const int d = m - 32;
          dl[(long)d * NBL + n] = softplusf_(v + dtb[d]);
        }
      }
}

// ---------------- merged-direction selective scan ----------------
// 512 blocks x 4 waves; wave = one (b,d) row, both directions.
static __device__ __forceinline__ void scan_pass(
    const float* __restrict__ dp, const float* __restrict__ up,
    const float* __restrict__ bct, const float* __restrict__ Alog,
    float Dv, int lane, float out[8], float u[8]) {
  float dt[8], dtu[8];
  {
    const float4 a0 = *(const float4*)&dp[0];
    const float4 a1 = *(const float4*)&dp[4];
    dt[0] = a0.x; dt[1] = a0.y; dt[2] = a0.z; dt[3] = a0.w;
    dt[4] = a1.x; dt[5] = a1.y; dt[6] = a1.z; dt[7] = a1.w;
    const float4 b0 = *(const float4*)&up[0];
    const float4 b1 = *(const float4*)&up[4];
    u[0] = b0.x; u[1] = b0.y; u[2] = b0.z; u[3] = b0.w;
    u[4] = b1.x; u[5] = b1.y; u[6] = b1.z; u[7] = b1.w;
  }
  #pragma unroll
  for (int j = 0; j < 8; ++j) { dtu[j] = dt[j] * u[j]; out[j] = 0.f; }

  for (int n = 0; n < DSTATE; ++n) {
    const float An = -__expf(Alog[n]);
    float Bv[8], Cv[8], dA[8], cB[8];
    {
      const float* bp = bct + (long)n * NBL;
      const float* cp = bct + (long)(DSTATE + n) * NBL;
      const float4 b0 = *(const float4*)&bp[0];
      const float4 b1 = *(const float4*)&bp[4];
      Bv[0] = b0.x; Bv[1] = b0.y; Bv[2] = b0.z; Bv[3] = b0.w;
      Bv[4] = b1.x; Bv[5] = b1.y; Bv[6] = b1.z; Bv[7] = b1.w;
      const float4 c0 = *(const float4*)&cp[0];
      const float4 c1 = *(const float4*)&cp[4];
      Cv[0] = c0.x; Cv[1] = c0.y; Cv[2] = c0.z; Cv[3] = c0.w;
      Cv[4] = c1.x; Cv[5] = c1.y; Cv[6] = c1.z; Cv[7] = c1.w;
    }
    float h = 0.f, P = 1.f;
    #pragma unroll
    for (int j = 0; j < 8; ++j) {
      dA[j] = __expf(dt[j] * An);
      cB[j] = dtu[j] * Bv[j];
      h = fmaf(h, dA[j], cB[j]);
      P *= dA[j];
    }
    float hs = h, Ps = P;
    #pragma unroll
    for (int off = 1; off < 64; off <<= 1) {
      const float hp = __shfl_up(hs, off, 64);
      const float Pp = __shfl_up(Ps, off, 64);
      if (lane >= off) { hs = fmaf(hp, Ps, hs); Ps *= Pp; }
    }
    float h0 = __shfl_up(hs, 1, 64);
    if (lane == 0) h0 = 0.f;
    #pragma unroll
    for (int j = 0; j < 8; ++j) {
      h0 = fmaf(h0, dA[j], cB[j]);
      out[j] = fmaf(h0, Cv[j], out[j]);
    }
  }
  #pragma unroll
  for (int j = 0; j < 8; ++j) out[j] = fmaf(Dv, u[j], out[j]);
}

__global__ __launch_bounds__(256) void scan_merged_kernel(
    const float* __restrict__ delta_f, const float* __restrict__ delta_r,
    const float* __restrict__ xconv_f, const float* __restrict__ xconv_r,
    const float* __restrict__ xbc_f, const float* __restrict__ xbc_r,
    const float* __restrict__ Alog_f, const float* __restrict__ Alog_r,
    const float* __restrict__ Dsk_f, const float* __restrict__ Dsk_r,
    const float* __restrict__ xz, float* __restrict__ y) {
  const int t = threadIdx.x;
  const int wv = t >> 6;
  const int lane = t & 63;
  const int row = blockIdx.x * 4 + wv;          // 0..2047
  const int b = row >> 10, d = row & 1023;
  const long rbase = (long)d * NBL + b * SEQ;

  float af[8], ar[8], uf[8], ur[8];
  scan_pass(delta_f + rbase + lane * 8, xconv_f + rbase + lane * 8,
            xbc_f + b * SEQ + lane * 8, Alog_f + d * DSTATE,
            Dsk_f[d], lane, af, uf);
  scan_pass(delta_r + rbase + lane * 8, xconv_r + rbase + lane * 8,
            xbc_r + b * SEQ + lane * 8, Alog_r + d * DSTATE,
            Dsk_r[d], lane, ar, ur);

  // mirror reverse result into forward order: pos p=lane*8+j gets
  // ar[7-j] from lane 63-lane, then apply the shared silu(z) gate.
  const float* zp = xz + (long)(DINNER + d) * NBL + b * SEQ + lane * 8;
  float* yp = y + rbase + lane * 8;
  const float4 z0 = *(const float4*)&zp[0];
  const float4 z1 = *(const float4*)&zp[4];
  const float zv[8] = {z0.x, z0.y, z0.z, z0.w, z1.x, z1.y, z1.z, z1.w};
  float out[8];
  #pragma unroll
  for (int j = 0; j < 8; ++j) {
    const float v = __shfl(ar[7 - j], 63 - lane, 64);
    out[j] = (af[j] + v) * (zv[j] * sigmoidf_(zv[j]));
  }
  float4 o0 = {out[0], out[1], out[2], out[3]};
  float4 o1 = {out[4], out[5], out[6], out[7]};
  *(float4*)&yp[0] = o0;
  *(float4*)&yp[4] = o1;
}

// ---------------- y transpose + bf16: ybt[n][e] = y[e][n] ----------------
__global__ __launch_bounds__(256) void ytrans_kernel(
    const float* __restrict__ yf, unsigned short* __restrict__ yt) {
  __shared__ unsigned short tile[32][33];
  const int e0 = blockIdx.y * 32, n0 = blockIdx.x * 32;
  const int t = threadIdx.x;
  const int c = t & 31, r8 = t >> 5;
  #pragma unroll
  for (int p = 0; p < 4; ++p) {
    const int e = e0 + p * 8 + r8;
    tile[p * 8 + r8][c] = f2bf(yf[(long)e * NBL + n0 + c]);
  }
  __syncthreads();
  #pragma unroll
  for (int p = 0; p < 4; ++p) {
    const int n = n0 + p * 8 + r8;
    yt[(long)n * DINNER + e0 + c] = tile[c][p * 8 + r8];
  }
}

// ---------------- out_proj GEMM: 128x128, BK=64, reg-prefetch ---------------
__global__ __launch_bounds__(256) void gemm_out_kernel(
    const unsigned short* __restrict__ A, const unsigned short* __restrict__ B,
    float* __restrict__ C, float* __restrict__ C2) {
  __shared__ unsigned short As[128 * LDK2];
  __shared__ unsigned short Bs[128 * LDK2];
  const int t = threadIdx.x;
  const int m0 = blockIdx.y * 128, n0 = blockIdx.x * 128;
  const int lane = t & 63;
  const int w = t >> 6;
  const int wr = (w >> 1) * 64, wc = (w & 1) * 64;
  const int fr = lane & 15;
  const int fq = lane >> 4;
  const int K = DINNER;

  f32x4 acc[4][4];
  #pragma unroll
  for (int i = 0; i < 4; ++i)
    #pragma unroll
    for (int j = 0; j < 4; ++j) {
      f32x4 z = {0.f, 0.f, 0.f, 0.f};
      acc[i][j] = z;
    }

  const int srow = t >> 1, sko = (t & 1) * 32;

  bf16x8 pa[4], pb[4];
  #define LOADG_OUT(k0_) do {                                              \
    const unsigned short* ap = &A[(long)(m0 + srow) * K + (k0_) + sko];    \
    pa[0] = *(const bf16x8*)ap;        pa[1] = *(const bf16x8*)(ap + 8);   \
    pa[2] = *(const bf16x8*)(ap + 16); pa[3] = *(const bf16x8*)(ap + 24);  \
    const unsigned short* bp = &B[(long)(n0 + srow) * K + (k0_) + sko];    \
    pb[0] = *(const bf16x8*)bp;        pb[1] = *(const bf16x8*)(bp + 8);   \
    pb[2] = *(const bf16x8*)(bp + 16); pb[3] = *(const bf16x8*)(bp + 24);  \
  } while (0)

  LOADG_OUT(0);
  for (int k0 = 0; k0 < K; k0 += 64) {
    if (k0) __syncthreads();
    *(bf16x8*)&As[srow * LDK2 + sko]      = pa[0];
    *(bf16x8*)&As[srow * LDK2 + sko + 8]  = pa[1];
    *(bf16x8*)&As[srow * LDK2 + sko + 16] = pa[2];
    *(bf16x8*)&As[srow * LDK2 + sko + 24] = pa[3];
    *(bf16x8*)&Bs[srow * LDK2 + sko]      = pb[0];
    *(bf16x8*)&Bs[srow * LDK2 + sko + 8]  = pb[1];
    *(bf16x8*)&Bs[srow * LDK2 + sko + 16] = pb[2];
    *(bf16x8*)&Bs[srow * LDK2 + sko + 24] = pb[3];
    __syncthreads();
    if (k0 + 64 < K) LOADG_OUT(k0 + 64);
    #pragma unroll
    for (int h = 0; h < 2; ++h) {
      bf16x8 af[4], bg[4];
      #pragma unroll
      for (int i = 0; i < 4; ++i) {
        af[i] = *(const bf16x8*)&As[(wr + i * 16 + fr) * LDK2 + h * 32 + fq * 8];
        bg[i] = *(const bf16x8*)&Bs[(wc + i * 16 + fr) * LDK2 + h * 32 + fq * 8];
      }
      #pragma unroll
      for (int i = 0; i < 4; ++i)
        #pragma unroll
        for (int j = 0; j < 4; ++j)
          acc[i][j] = __builtin_amdgcn_mfma_f32_16x16x32_bf16(
              af[i], bg[j], acc[i][j], 0, 0, 0);
    }
  }
  #undef LOADG_OUT

  #pragma unroll
  for (int i = 0; i < 4; ++i)
    #pragma unroll
    for (int j = 0; j < 4; ++j)
      #pragma unroll
      for (int r2 = 0; r2 < 4; ++r2) {
        const int m = m0 + wr + i * 16 + fq * 4 + r2;
        const int n = n0 + wc + j * 16 + fr;
        const long addr = (long)n * DMODEL + m;
        C[addr] = acc[i][j][r2];
        C2[addr] = acc[i][j][r2];
      }
}

extern "C" void kernel_launch(void* const* d_in, const int* in_sizes, int n_in,
                              void* d_out, int out_size, void* d_ws, size_t ws_size,
                              hipStream_t stream) {
  (void)in_sizes; (void)n_in; (void)out_size; (void)ws_size;
  const float* x       = (const float*)d_in[0];
  const float* norm_w  = (const float*)d_in[1];
  const float* in_proj = (const float*)d_in[2];
  const float* convw_f = (const float*)d_in[3];
  const float* convb_f = (const float*)d_in[4];
  const float* xpw_f   = (const float*)d_in[5];
  const float* dtw_f   = (const float*)d_in[6];
  const float* dtb_f   = (const float*)d_in[7];
  const float* Alog_f  = (const float*)d_in[8];
  const float* Dsk_f   = (const float*)d_in[9];
  const float* convw_r = (const float*)d_in[10];
  const float* convb_r = (const float*)d_in[11];
  const float* xpw_r   = (const float*)d_in[12];
  const float* dtw_r   = (const float*)d_in[13];
  const float* dtb_r   = (const float*)d_in[14];
  const float* Alog_r  = (const float*)d_in[15];
  const float* Dsk_r   = (const float*)d_in[16];
  const float* out_w   = (const float*)d_in[17];
  const float* normf_w = (const float*)d_in[18];

  float* ws = (float*)d_ws;
  float* residual = ws;  ws += 524288;
  float* xzbuf    = ws;  ws += 2097152;
  float* xconv_f  = ws;  ws += 1048576;
  float* xconv_r  = ws;  ws += 1048576;
  float* xbc_f    = ws;  ws += 32768;
  float* xbc_r    = ws;  ws += 32768;
  float* delta_f  = ws;  ws += 1048576;
  float* delta_r  = ws;  ws += 1048576;
  float* ybuf     = ws;  ws += 1048576;
  float* hs       = ws;  ws += 524288;
  float* hnb_f    = ws;  ws += 262144;   // 1024x512 bf16
  float* wbfin_f  = ws;  ws += 2097152;  // 4x2048x512 bf16
  float* wbfout_f = ws;  ws += 1048576;  // 4x512x1024 bf16
  float* ybt_f    = ws;  ws += 524288;   // 1024x1024 bf16
  float* xcT_f    = ws;  ws += 1048576;  // 2 x 1024 x 1024 bf16
  float* xpwb_f_  = ws;  ws += 131072;
  float* xpwb_r_  = ws;  ws += 131072;
  float* dtwb_f_  = ws;  ws += 65536;
  float* dtwb_r_  = ws;  ws += 65536;
  float* xpwT_f   = ws;  ws += 131072;   // 8 x 1024 x 32 bf16
  float* Acomb_f  = ws;  ws += 4718592;  // 8 x 1152 x 1024 bf16

  unsigned short* hnb = (unsigned short*)hnb_f;
  unsigned short* wbfin = (unsigned short*)wbfin_f;
  unsigned short* wbfout = (unsigned short*)wbfout_f;
  unsigned short* ybt = (unsigned short*)ybt_f;
  unsigned short* xcT = (unsigned short*)xcT_f;
  unsigned short* xpwb_f = (unsigned short*)xpwb_f_;
  unsigned short* xpwb_r = (unsigned short*)xpwb_r_;
  unsigned short* dtwb_f = (unsigned short*)dtwb_f_;
  unsigned short* dtwb_r = (unsigned short*)dtwb_r_;
  unsigned short* xpwT = (unsigned short*)xpwT_f;
  unsigned short* Acomb = (unsigned short*)Acomb_f;

  float* outp = (float*)d_out;

  wconvert_kernel<<<3456, 256, 0, stream>>>(
      in_proj, out_w, xpw_f, xpw_r, dtw_f, dtw_r,
      wbfin, wbfout, xpwb_f, xpwb_r, dtwb_f, dtwb_r);
  prep_kernel<<<dim3(32, 8), 256, 0, stream>>>(xpwb_f, xpwb_r, xpwT, Acomb);
  wdelta_kernel<<<dim3(8, 8, 8), 256, 0, stream>>>(dtwb_f, dtwb_r, xpwT, Acomb);

  for (int layer = 0; layer < 4; ++layer) {
    addnorm_kernel<<<1024, 256, 0, stream>>>(
        layer == 0 ? x : hs, residual, norm_w + layer * DMODEL,
        nullptr, hnb, layer == 0 ? 1 : 0);
    gemm_in_kernel<<<dim3(16, 16), 256, 0, stream>>>(
        wbfin + (long)layer * 2048 * 512, hnb, xzbuf);
    conv_silu_kernel<<<dim3(32, 32, 2), 256, 0, stream>>>(
        xzbuf, convw_f + layer * DINNER * 4, convb_f + layer * DINNER,
        convw_r + layer * DINNER * 4, convb_r + layer * DINNER,
        xconv_f, xconv_r, xcT);
    fusedproj_kernel<<<dim3(8, 9, 2), 256, 0, stream>>>(
        Acomb, xcT, dtb_f, dtb_r, xbc_f, xbc_r, delta_f, delta_r, layer);
    scan_merged_kernel<<<512, 256, 0, stream>>>(
        delta_f, delta_r, xconv_f, xconv_r, xbc_f, xbc_r,
        Alog_f + layer * DINNER * DSTATE, Alog_r + layer * DINNER * DSTATE,
        Dsk_f + layer * DINNER, Dsk_r + layer * DINNER,
        xzbuf, ybuf);
    ytrans_kernel<<<dim3(32, 32), 256, 0, stream>>>(ybuf, ybt);
    gemm_out_kernel<<<dim3(8, 4), 256, 0, stream>>>(
        wbfout + (long)layer * 512 * 1024, ybt, hs,
        outp + (long)(1 + layer) * 524288);
  }
  addnorm_kernel<<<1024, 256, 0, stream>>>(hs, residual, normf_w, outp, nullptr, 0);
}

// Round 12
// 390.145 us; speedup vs baseline: 1.1798x; 1.1798x over previous
//
#include <hip/hip_runtime.h>

#define BATCH 2
#define SEQ 512
#define DMODEL 512
#define DINNER 1024
#define DSTATE 16
#define DTRANK 32
#define NBL (BATCH*SEQ)      // 1024
#define EPSV 1e-5f

typedef __attribute__((ext_vector_type(8))) short bf16x8;
typedef __attribute__((ext_vector_type(4))) float f32x4;

static __device__ __forceinline__ float sigmoidf_(float x) {
  return 1.0f / (1.0f + __expf(-x));
}
static __device__ __forceinline__ float softplusf_(float x) {
  return fmaxf(x, 0.0f) + log1pf(__expf(-fabsf(x)));
}
static __device__ __forceinline__ unsigned short f2bf(float x) {
  unsigned int u = __float_as_uint(x);
  unsigned int r = (u + 0x7FFFu + ((u >> 16) & 1u)) >> 16;
  return (unsigned short)r;
}

// ---------------- all-weight fp32 -> bf16 convert (segmented) ----------------
__global__ __launch_bounds__(256) void wconvert_kernel(
    const float* __restrict__ s0, const float* __restrict__ s1,
    const float* __restrict__ s2, const float* __restrict__ s3,
    const float* __restrict__ s4, const float* __restrict__ s5,
    unsigned short* __restrict__ d0, unsigned short* __restrict__ d1,
    unsigned short* __restrict__ d2, unsigned short* __restrict__ d3,
    unsigned short* __restrict__ d4, unsigned short* __restrict__ d5) {
  long i = (long)(blockIdx.x * 256 + threadIdx.x) * 8;
  const float* src; unsigned short* dst;
  if (i < 4194304)      { src = s0; dst = d0; }
  else if (i < 6291456) { src = s1; dst = d1; i -= 4194304; }
  else if (i < 6553600) { src = s2; dst = d2; i -= 6291456; }
  else if (i < 6815744) { src = s3; dst = d3; i -= 6553600; }
  else if (i < 6946816) { src = s4; dst = d4; i -= 6815744; }
  else                  { src = s5; dst = d5; i -= 6946816; }
  const float4 v0 = *(const float4*)&src[i];
  const float4 v1 = *(const float4*)&src[i + 4];
  bf16x8 o;
  o[0] = (short)f2bf(v0.x); o[1] = (short)f2bf(v0.y);
  o[2] = (short)f2bf(v0.z); o[3] = (short)f2bf(v0.w);
  o[4] = (short)f2bf(v1.x); o[5] = (short)f2bf(v1.y);
  o[6] = (short)f2bf(v1.z); o[7] = (short)f2bf(v1.w);
  *(bf16x8*)&dst[i] = o;
}

// ---------------- fused add + RMSNorm ----------------
__global__ __launch_bounds__(256) void addnorm_kernel(
    const float* __restrict__ hs, float* __restrict__ residual,
    const float* __restrict__ w, float* __restrict__ out,
    unsigned short* __restrict__ outb, int first) {
  const int row = blockIdx.x;
  const int t = threadIdx.x;
  const float* hp = hs + (long)row * DMODEL;
  float* rp = residual + (long)row * DMODEL;
  float r0 = hp[t], r1 = hp[t + 256];
  if (!first) { r0 += rp[t]; r1 += rp[t + 256]; }
  rp[t] = r0; rp[t + 256] = r1;
  float ss = r0 * r0 + r1 * r1;
  #pragma unroll
  for (int off = 32; off; off >>= 1) ss += __shfl_xor(ss, off, 64);
  __shared__ float sw[4];
  const int wid = t >> 6, lane = t & 63;
  if (lane == 0) sw[wid] = ss;
  __syncthreads();
  const float tot = sw[0] + sw[1] + sw[2] + sw[3];
  const float scale = rsqrtf(tot * (1.0f / (float)DMODEL) + EPSV);
  const float v0 = r0 * scale * w[t];
  const float v1 = r1 * scale * w[t + 256];
  if (out) {
    out[(long)row * DMODEL + t] = v0;
    out[(long)row * DMODEL + t + 256] = v1;
  }
  if (outb) {
    outb[(long)row * DMODEL + t] = f2bf(v0);
    outb[(long)row * DMODEL + t + 256] = f2bf(v1);
  }
}

#define LDK 40
#define LDK2 72

// ---------------- in_proj GEMM: 128M x 64N, BK=64, reg-prefetch -------------
__global__ __launch_bounds__(256) void gemm_in_kernel(
    const unsigned short* __restrict__ A, const unsigned short* __restrict__ B,
    float* __restrict__ C) {
  __shared__ unsigned short As[128 * LDK2];
  __shared__ unsigned short Bs[64 * LDK2];
  const int t = threadIdx.x;
  const int m0 = blockIdx.y * 128, n0 = blockIdx.x * 64;
  const int lane = t & 63;
  const int w = t >> 6;
  const int wr = (w >> 1) * 64, wc = (w & 1) * 32;
  const int fr = lane & 15;
  const int fq = lane >> 4;
  const int K = DMODEL;

  f32x4 acc[4][2];
  #pragma unroll
  for (int i = 0; i < 4; ++i)
    #pragma unroll
    for (int j = 0; j < 2; ++j) {
      f32x4 z = {0.f, 0.f, 0.f, 0.f};
      acc[i][j] = z;
    }

  const int arow = t >> 1, ako = (t & 1) * 32;   // A: 128 x 64
  const int brow = t >> 2, bko = (t & 3) * 16;   // B: 64 x 64

  bf16x8 pa[4], pb[2];
  #define LOADG_IN(k0_) do {                                              \
    const unsigned short* ap = &A[(long)(m0 + arow) * K + (k0_) + ako];   \
    pa[0] = *(const bf16x8*)ap;        pa[1] = *(const bf16x8*)(ap + 8);  \
    pa[2] = *(const bf16x8*)(ap + 16); pa[3] = *(const bf16x8*)(ap + 24); \
    const unsigned short* bp = &B[(long)(n0 + brow) * K + (k0_) + bko];   \
    pb[0] = *(const bf16x8*)bp;        pb[1] = *(const bf16x8*)(bp + 8);  \
  } while (0)

  LOADG_IN(0);
  for (int k0 = 0; k0 < K; k0 += 64) {
    if (k0) __syncthreads();
    *(bf16x8*)&As[arow * LDK2 + ako]      = pa[0];
    *(bf16x8*)&As[arow * LDK2 + ako + 8]  = pa[1];
    *(bf16x8*)&As[arow * LDK2 + ako + 16] = pa[2];
    *(bf16x8*)&As[arow * LDK2 + ako + 24] = pa[3];
    *(bf16x8*)&Bs[brow * LDK2 + bko]      = pb[0];
    *(bf16x8*)&Bs[brow * LDK2 + bko + 8]  = pb[1];
    __syncthreads();
    if (k0 + 64 < K) LOADG_IN(k0 + 64);
    #pragma unroll
    for (int h = 0; h < 2; ++h) {
      bf16x8 af[4], bg[2];
      #pragma unroll
      for (int i = 0; i < 4; ++i)
        af[i] = *(const bf16x8*)&As[(wr + i * 16 + fr) * LDK2 + h * 32 + fq * 8];
      #pragma unroll
      for (int j = 0; j < 2; ++j)
        bg[j] = *(const bf16x8*)&Bs[(wc + j * 16 + fr) * LDK2 + h * 32 + fq * 8];
      #pragma unroll
      for (int i = 0; i < 4; ++i)
        #pragma unroll
        for (int j = 0; j < 2; ++j)
          acc[i][j] = __builtin_amdgcn_mfma_f32_16x16x32_bf16(
              af[i], bg[j], acc[i][j], 0, 0, 0);
    }
  }
  #undef LOADG_IN

  #pragma unroll
  for (int i = 0; i < 4; ++i)
    #pragma unroll
    for (int j = 0; j < 2; ++j)
      #pragma unroll
      for (int r2 = 0; r2 < 4; ++r2) {
        const int m = m0 + wr + i * 16 + fq * 4 + r2;
        const int n = n0 + wc + j * 16 + fr;
        C[(long)m * NBL + n] = acc[i][j][r2];
      }
}

// ---------------- conv+SiLU + transposed bf16 out (fused xct) ----------------
__global__ __launch_bounds__(256) void conv_silu_kernel(
    const float* __restrict__ xz,
    const float* __restrict__ cw_f, const float* __restrict__ cb_f,
    const float* __restrict__ cw_r, const float* __restrict__ cb_r,
    float* __restrict__ xconv_f, float* __restrict__ xconv_r,
    unsigned short* __restrict__ xcT) {
  __shared__ unsigned short tile[32][33];
  const int dir = blockIdx.z;
  const int n0 = blockIdx.x * 32, d0 = blockIdx.y * 32;
  const int b = n0 >> 9;
  const int l0 = n0 & (SEQ - 1);
  const float* cw = dir ? cw_r : cw_f;
  const float* cb = dir ? cb_r : cb_f;
  float* xconv = dir ? xconv_r : xconv_f;
  unsigned short* dst = xcT + (long)dir * DINNER * NBL;
  const int t = threadIdx.x;
  const int c = t & 31, rr = t >> 5;
  #pragma unroll
  for (int p = 0; p < 4; ++p) {
    const int d = d0 + p * 8 + rr;
    const int l = l0 + c;
    const float* xi = xz + (long)d * NBL + b * SEQ;
    float sum = cb[d];
    #pragma unroll
    for (int k = 0; k < 4; ++k) {
      const int tt = l - 3 + k;
      if (tt >= 0) {
        const int src = dir ? (SEQ - 1 - tt) : tt;
        sum += cw[d * 4 + k] * xi[src];
      }
    }
    const float v = sum * sigmoidf_(sum);
    xconv[(long)d * NBL + n0 + c] = v;
    tile[p * 8 + rr][c] = f2bf(v);
  }
  __syncthreads();
  #pragma unroll
  for (int p = 0; p < 4; ++p) {
    const int n = n0 + p * 8 + rr;
    dst[(long)n * DINNER + d0 + c] = tile[c][p * 8 + rr];
  }
}

// ---------------- x_dbl via MFMA: 64M x 128N, BK=64, reg-prefetch -----------
// rows<32 -> dtT bf16 (dir,n,32); rows>=32 -> xbcT fp32 [slot][NBL].
__global__ __launch_bounds__(256) void xdbl_mfma_kernel(
    const unsigned short* __restrict__ xpwb_f, const unsigned short* __restrict__ xpwb_r,
    const unsigned short* __restrict__ xcT,
    unsigned short* __restrict__ dtT,
    float* __restrict__ xbc_f, float* __restrict__ xbc_r) {
  __shared__ unsigned short As[64 * LDK2];
  __shared__ unsigned short Bs[128 * LDK2];
  const int t = threadIdx.x;
  const int dir = blockIdx.y;
  const int n0 = blockIdx.x * 128;
  const unsigned short* A = dir ? xpwb_r : xpwb_f;
  const unsigned short* B = xcT + (long)dir * DINNER * NBL;
  float* xbc = dir ? xbc_r : xbc_f;
  unsigned short* dtt = dtT + (long)dir * NBL * DTRANK;

  const int lane = t & 63;
  const int w = t >> 6;
  const int fr = lane & 15;
  const int fq = lane >> 4;

  f32x4 acc[4][2];
  #pragma unroll
  for (int i = 0; i < 4; ++i)
    #pragma unroll
    for (int j = 0; j < 2; ++j) {
      f32x4 z = {0.f, 0.f, 0.f, 0.f};
      acc[i][j] = z;
    }

  const int arow = t >> 2, ako = (t & 3) * 16;   // A: 64 x 64
  const int brow = t >> 1, bko = (t & 1) * 32;   // B: 128 x 64

  bf16x8 pa[2], pb[4];
  #define LOADG_XD(k0_) do {                                                   \
    const unsigned short* ap = &A[(long)arow * DINNER + (k0_) + ako];          \
    pa[0] = *(const bf16x8*)ap;        pa[1] = *(const bf16x8*)(ap + 8);       \
    const unsigned short* bp = &B[(long)(n0 + brow) * DINNER + (k0_) + bko];   \
    pb[0] = *(const bf16x8*)bp;        pb[1] = *(const bf16x8*)(bp + 8);       \
    pb[2] = *(const bf16x8*)(bp + 16); pb[3] = *(const bf16x8*)(bp + 24);      \
  } while (0)

  LOADG_XD(0);
  for (int k0 = 0; k0 < DINNER; k0 += 64) {
    if (k0) __syncthreads();
    *(bf16x8*)&As[arow * LDK2 + ako]      = pa[0];
    *(bf16x8*)&As[arow * LDK2 + ako + 8]  = pa[1];
    *(bf16x8*)&Bs[brow * LDK2 + bko]      = pb[0];
    *(bf16x8*)&Bs[brow * LDK2 + bko + 8]  = pb[1];
    *(bf16x8*)&Bs[brow * LDK2 + bko + 16] = pb[2];
    *(bf16x8*)&Bs[brow * LDK2 + bko + 24] = pb[3];
    __syncthreads();
    if (k0 + 64 < DINNER) LOADG_XD(k0 + 64);
    #pragma unroll
    for (int h = 0; h < 2; ++h) {
      bf16x8 af[4], bg[2];
      #pragma unroll
      for (int i = 0; i < 4; ++i)
        af[i] = *(const bf16x8*)&As[(i * 16 + fr) * LDK2 + h * 32 + fq * 8];
      #pragma unroll
      for (int j = 0; j < 2; ++j)
        bg[j] = *(const bf16x8*)&Bs[(w * 32 + j * 16 + fr) * LDK2 + h * 32 + fq * 8];
      #pragma unroll
      for (int i = 0; i < 4; ++i)
        #pragma unroll
        for (int j = 0; j < 2; ++j)
          acc[i][j] = __builtin_amdgcn_mfma_f32_16x16x32_bf16(
              af[i], bg[j], acc[i][j], 0, 0, 0);
    }
  }
  #undef LOADG_XD

  #pragma unroll
  for (int i = 0; i < 4; ++i)
    #pragma unroll
    for (int j = 0; j < 2; ++j)
      #pragma unroll
      for (int r2 = 0; r2 < 4; ++r2) {
        const int m = i * 16 + fq * 4 + r2;
        const int n = n0 + w * 32 + j * 16 + fr;
        const float v = acc[i][j][r2];
        if (m < DTRANK) dtt[(long)n * DTRANK + m] = f2bf(v);
        else xbc[(long)(m - 32) * NBL + n] = v;   // slot-major
      }
}

// ---------------- delta via MFMA: softplus(dtw @ dt + dtb) ----------------
__global__ __launch_bounds__(256) void deltam_kernel(
    const unsigned short* __restrict__ dtwb_f, const unsigned short* __restrict__ dtwb_r,
    const unsigned short* __restrict__ dtT,
    const float* __restrict__ dtb_f, const float* __restrict__ dtb_r,
    float* __restrict__ delta_f, float* __restrict__ delta_r) {
  __shared__ unsigned short As[128 * LDK];
  __shared__ unsigned short Bs[128 * LDK];
  const int t = threadIdx.x;
  const int dir = blockIdx.z;
  const unsigned short* A = dir ? dtwb_r : dtwb_f;
  const unsigned short* B = dtT + (long)dir * NBL * DTRANK;
  const float* dtb = dir ? dtb_r : dtb_f;
  float* dl = dir ? delta_r : delta_f;
  const int m0 = blockIdx.y * 128, n0 = blockIdx.x * 128;
  const int lane = t & 63;
  const int w = t >> 6;
  const int wr = (w >> 1) * 64, wc = (w & 1) * 64;
  const int fr = lane & 15;
  const int fq = lane >> 4;

  const int srow = t >> 1;
  const int sko = (t & 1) * 16;
  *(bf16x8*)&As[srow * LDK + sko] =
      *(const bf16x8*)&A[(long)(m0 + srow) * DTRANK + sko];
  *(bf16x8*)&As[srow * LDK + sko + 8] =
      *(const bf16x8*)&A[(long)(m0 + srow) * DTRANK + sko + 8];
  *(bf16x8*)&Bs[srow * LDK + sko] =
      *(const bf16x8*)&B[(long)(n0 + srow) * DTRANK + sko];
  *(bf16x8*)&Bs[srow * LDK + sko + 8] =
      *(const bf16x8*)&B[(long)(n0 + srow) * DTRANK + sko + 8];
  __syncthreads();

  bf16x8 af[4], bg[4];
  #pragma unroll
  for (int i = 0; i < 4; ++i) {
    af[i] = *(const bf16x8*)&As[(wr + i * 16 + fr) * LDK + fq * 8];
    bg[i] = *(const bf16x8*)&Bs[(wc + i * 16 + fr) * LDK + fq * 8];
  }
  f32x4 acc[4][4];
  #pragma unroll
  for (int i = 0; i < 4; ++i)
    #pragma unroll
    for (int j = 0; j < 4; ++j) {
      f32x4 z = {0.f, 0.f, 0.f, 0.f};
      acc[i][j] = __builtin_amdgcn_mfma_f32_16x16x32_bf16(af[i], bg[j], z, 0, 0, 0);
    }

  #pragma unroll
  for (int i = 0; i < 4; ++i) {
    const int m = m0 + wr + i * 16 + fq * 4;
    #pragma unroll
    for (int r2 = 0; r2 < 4; ++r2) {
      const float bias = dtb[m + r2];
      #pragma unroll
      for (int j = 0; j < 4; ++j) {
        const int n = n0 + wc + j * 16 + fr;
        dl[(long)(m + r2) * NBL + n] = softplusf_(acc[i][j][r2] + bias);
      }
    }
  }
}

// ---------------- merged-direction selective scan ----------------
static __device__ __forceinline__ void scan_pass(
    const float* __restrict__ dp, const float* __restrict__ up,
    const float* __restrict__ bct, const float* __restrict__ Alog,
    float Dv, int lane, float out[8], float u[8]) {
  float dt[8], dtu[8];
  {
    const float4 a0 = *(const float4*)&dp[0];
    const float4 a1 = *(const float4*)&dp[4];
    dt[0] = a0.x; dt[1] = a0.y; dt[2] = a0.z; dt[3] = a0.w;
    dt[4] = a1.x; dt[5] = a1.y; dt[6] = a1.z; dt[7] = a1.w;
    const float4 b0 = *(const float4*)&up[0];
    const float4 b1 = *(const float4*)&up[4];
    u[0] = b0.x; u[1] = b0.y; u[2] = b0.z; u[3] = b0.w;
    u[4] = b1.x; u[5] = b1.y; u[6] = b1.z; u[7] = b1.w;
  }
  #pragma unroll
  for (int j = 0; j < 8; ++j) { dtu[j] = dt[j] * u[j]; out[j] = 0.f; }

  for (int n = 0; n < DSTATE; ++n) {
    const float An = -__expf(Alog[n]);
    float Bv[8], Cv[8], dA[8], cB[8];
    {
      const float* bp = bct + (long)n * NBL;
      const float* cp = bct + (long)(DSTATE + n) * NBL;
      const float4 b0 = *(const float4*)&bp[0];
      const float4 b1 = *(const float4*)&bp[4];
      Bv[0] = b0.x; Bv[1] = b0.y; Bv[2] = b0.z; Bv[3] = b0.w;
      Bv[4] = b1.x; Bv[5] = b1.y; Bv[6] = b1.z; Bv[7] = b1.w;
      const float4 c0 = *(const float4*)&cp[0];
      const float4 c1 = *(const float4*)&cp[4];
      Cv[0] = c0.x; Cv[1] = c0.y; Cv[2] = c0.z; Cv[3] = c0.w;
      Cv[4] = c1.x; Cv[5] = c1.y; Cv[6] = c1.z; Cv[7] = c1.w;
    }
    float h = 0.f, P = 1.f;
    #pragma unroll
    for (int j = 0; j < 8; ++j) {
      dA[j] = __expf(dt[j] * An);
      cB[j] = dtu[j] * Bv[j];
      h = fmaf(h, dA[j], cB[j]);
      P *= dA[j];
    }
    float hs = h, Ps = P;
    #pragma unroll
    for (int off = 1; off < 64; off <<= 1) {
      const float hp = __shfl_up(hs, off, 64);
      const float Pp = __shfl_up(Ps, off, 64);
      if (lane >= off) { hs = fmaf(hp, Ps, hs); Ps *= Pp; }
    }
    float h0 = __shfl_up(hs, 1, 64);
    if (lane == 0) h0 = 0.f;
    #pragma unroll
    for (int j = 0; j < 8; ++j) {
      h0 = fmaf(h0, dA[j], cB[j]);
      out[j] = fmaf(h0, Cv[j], out[j]);
    }
  }
  #pragma unroll
  for (int j = 0; j < 8; ++j) out[j] = fmaf(Dv, u[j], out[j]);
}

__global__ __launch_bounds__(256) void scan_merged_kernel(
    const float* __restrict__ delta_f, const float* __restrict__ delta_r,
    const float* __restrict__ xconv_f, const float* __restrict__ xconv_r,
    const float* __restrict__ xbc_f, const float* __restrict__ xbc_r,
    const float* __restrict__ Alog_f, const float* __restrict__ Alog_r,
    const float* __restrict__ Dsk_f, const float* __restrict__ Dsk_r,
    const float* __restrict__ xz, float* __restrict__ y) {
  const int t = threadIdx.x;
  const int wv = t >> 6;
  const int lane = t & 63;
  const int row = blockIdx.x * 4 + wv;          // 0..2047
  const int b = row >> 10, d = row & 1023;
  const long rbase = (long)d * NBL + b * SEQ;

  float af[8], ar[8], uf[8], ur[8];
  scan_pass(delta_f + rbase + lane * 8, xconv_f + rbase + lane * 8,
            xbc_f + b * SEQ + lane * 8, Alog_f + d * DSTATE,
            Dsk_f[d], lane, af, uf);
  scan_pass(delta_r + rbase + lane * 8, xconv_r + rbase + lane * 8,
            xbc_r + b * SEQ + lane * 8, Alog_r + d * DSTATE,
            Dsk_r[d], lane, ar, ur);

  const float* zp = xz + (long)(DINNER + d) * NBL + b * SEQ + lane * 8;
  float* yp = y + rbase + lane * 8;
  const float4 z0 = *(const float4*)&zp[0];
  const float4 z1 = *(const float4*)&zp[4];
  const float zv[8] = {z0.x, z0.y, z0.z, z0.w, z1.x, z1.y, z1.z, z1.w};
  float out[8];
  #pragma unroll
  for (int j = 0; j < 8; ++j) {
    const float v = __shfl(ar[7 - j], 63 - lane, 64);
    out[j] = (af[j] + v) * (zv[j] * sigmoidf_(zv[j]));
  }
  float4 o0 = {out[0], out[1], out[2], out[3]};
  float4 o1 = {out[4], out[5], out[6], out[7]};
  *(float4*)&yp[0] = o0;
  *(float4*)&yp[4] = o1;
}

// ---------------- y transpose + bf16: ybt[n][e] = y[e][n] ----------------
__global__ __launch_bounds__(256) void ytrans_kernel(
    const float* __restrict__ yf, unsigned short* __restrict__ yt) {
  __shared__ unsigned short tile[32][33];
  const int e0 = blockIdx.y * 32, n0 = blockIdx.x * 32;
  const int t = threadIdx.x;
  const int c = t & 31, r8 = t >> 5;
  #pragma unroll
  for (int p = 0; p < 4; ++p) {
    const int e = e0 + p * 8 + r8;
    tile[p * 8 + r8][c] = f2bf(yf[(long)e * NBL + n0 + c]);
  }
  __syncthreads();
  #pragma unroll
  for (int p = 0; p < 4; ++p) {
    const int n = n0 + p * 8 + r8;
    yt[(long)n * DINNER + e0 + c] = tile[c][p * 8 + r8];
  }
}

// ---------------- out_proj GEMM: 128x128, BK=64, reg-prefetch ---------------
// writes only to C (the d_out feats slot); next addnorm reads it directly.
__global__ __launch_bounds__(256) void gemm_out_kernel(
    const unsigned short* __restrict__ A, const unsigned short* __restrict__ B,
    float* __restrict__ C) {
  __shared__ unsigned short As[128 * LDK2];
  __shared__ unsigned short Bs[128 * LDK2];
  const int t = threadIdx.x;
  const int m0 = blockIdx.y * 128, n0 = blockIdx.x * 128;
  const int lane = t & 63;
  const int w = t >> 6;
  const int wr = (w >> 1) * 64, wc = (w & 1) * 64;
  const int fr = lane & 15;
  const int fq = lane >> 4;
  const int K = DINNER;

  f32x4 acc[4][4];
  #pragma unroll
  for (int i = 0; i < 4; ++i)
    #pragma unroll
    for (int j = 0; j < 4; ++j) {
      f32x4 z = {0.f, 0.f, 0.f, 0.f};
      acc[i][j] = z;
    }

  const int srow = t >> 1, sko = (t & 1) * 32;

  bf16x8 pa[4], pb[4];
  #define LOADG_OUT(k0_) do {                                              \
    const unsigned short* ap = &A[(long)(m0 + srow) * K + (k0_) + sko];    \
    pa[0] = *(const bf16x8*)ap;        pa[1] = *(const bf16x8*)(ap + 8);   \
    pa[2] = *(const bf16x8*)(ap + 16); pa[3] = *(const bf16x8*)(ap + 24);  \
    const unsigned short* bp = &B[(long)(n0 + srow) * K + (k0_) + sko];    \
    pb[0] = *(const bf16x8*)bp;        pb[1] = *(const bf16x8*)(bp + 8);   \
    pb[2] = *(const bf16x8*)(bp + 16); pb[3] = *(const bf16x8*)(bp + 24);  \
  } while (0)

  LOADG_OUT(0);
  for (int k0 = 0; k0 < K; k0 += 64) {
    if (k0) __syncthreads();
    *(bf16x8*)&As[srow * LDK2 + sko]      = pa[0];
    *(bf16x8*)&As[srow * LDK2 + sko + 8]  = pa[1];
    *(bf16x8*)&As[srow * LDK2 + sko + 16] = pa[2];
    *(bf16x8*)&As[srow * LDK2 + sko + 24] = pa[3];
    *(bf16x8*)&Bs[srow * LDK2 + sko]      = pb[0];
    *(bf16x8*)&Bs[srow * LDK2 + sko + 8]  = pb[1];
    *(bf16x8*)&Bs[srow * LDK2 + sko + 16] = pb[2];
    *(bf16x8*)&Bs[srow * LDK2 + sko + 24] = pb[3];
    __syncthreads();
    if (k0 + 64 < K) LOADG_OUT(k0 + 64);
    #pragma unroll
    for (int h = 0; h < 2; ++h) {
      bf16x8 af[4], bg[4];
      #pragma unroll
      for (int i = 0; i < 4; ++i) {
        af[i] = *(const bf16x8*)&As[(wr + i * 16 + fr) * LDK2 + h * 32 + fq * 8];
        bg[i] = *(const bf16x8*)&Bs[(wc + i * 16 + fr) * LDK2 + h * 32 + fq * 8];
      }
      #pragma unroll
      for (int i = 0; i < 4; ++i)
        #pragma unroll
        for (int j = 0; j < 4; ++j)
          acc[i][j] = __builtin_amdgcn_mfma_f32_16x16x32_bf16(
              af[i], bg[j], acc[i][j], 0, 0, 0);
    }
  }
  #undef LOADG_OUT

  #pragma unroll
  for (int i = 0; i < 4; ++i)
    #pragma unroll
    for (int j = 0; j < 4; ++j)
      #pragma unroll
      for (int r2 = 0; r2 < 4; ++r2) {
        const int m = m0 + wr + i * 16 + fq * 4 + r2;
        const int n = n0 + wc + j * 16 + fr;
        C[(long)n * DMODEL + m] = acc[i][j][r2];
      }
}

extern "C" void kernel_launch(void* const* d_in, const int* in_sizes, int n_in,
                              void* d_out, int out_size, void* d_ws, size_t ws_size,
                              hipStream_t stream) {
  (void)in_sizes; (void)n_in; (void)out_size; (void)ws_size;
  const float* x       = (const float*)d_in[0];
  const float* norm_w  = (const float*)d_in[1];
  const float* in_proj = (const float*)d_in[2];
  const float* convw_f = (const float*)d_in[3];
  const float* convb_f = (const float*)d_in[4];
  const float* xpw_f   = (const float*)d_in[5];
  const float* dtw_f   = (const float*)d_in[6];
  const float* dtb_f   = (const float*)d_in[7];
  const float* Alog_f  = (const float*)d_in[8];
  const float* Dsk_f   = (const float*)d_in[9];
  const float* convw_r = (const float*)d_in[10];
  const float* convb_r = (const float*)d_in[11];
  const float* xpw_r   = (const float*)d_in[12];
  const float* dtw_r   = (const float*)d_in[13];
  const float* dtb_r   = (const float*)d_in[14];
  const float* Alog_r  = (const float*)d_in[15];
  const float* Dsk_r   = (const float*)d_in[16];
  const float* out_w   = (const float*)d_in[17];
  const float* normf_w = (const float*)d_in[18];

  float* ws = (float*)d_ws;
  float* residual = ws;  ws += 524288;
  float* xzbuf    = ws;  ws += 2097152;
  float* xconv_f  = ws;  ws += 1048576;
  float* xconv_r  = ws;  ws += 1048576;
  float* xbc_f    = ws;  ws += 32768;
  float* xbc_r    = ws;  ws += 32768;
  float* delta_f  = ws;  ws += 1048576;
  float* delta_r  = ws;  ws += 1048576;
  float* ybuf     = ws;  ws += 1048576;
  float* hnb_f    = ws;  ws += 262144;   // 1024x512 bf16
  float* wbfin_f  = ws;  ws += 2097152;  // 4x2048x512 bf16
  float* wbfout_f = ws;  ws += 1048576;  // 4x512x1024 bf16
  float* ybt_f    = ws;  ws += 524288;   // 1024x1024 bf16
  float* xcT_f    = ws;  ws += 1048576;  // 2 x 1024 x 1024 bf16
  float* dtT_f    = ws;  ws += 32768;    // 2 x 1024 x 32 bf16
  float* xpwb_f_  = ws;  ws += 131072;
  float* xpwb_r_  = ws;  ws += 131072;
  float* dtwb_f_  = ws;  ws += 65536;
  float* dtwb_r_  = ws;  ws += 65536;

  unsigned short* hnb = (unsigned short*)hnb_f;
  unsigned short* wbfin = (unsigned short*)wbfin_f;
  unsigned short* wbfout = (unsigned short*)wbfout_f;
  unsigned short* ybt = (unsigned short*)ybt_f;
  unsigned short* xcT = (unsigned short*)xcT_f;
  unsigned short* dtT = (unsigned short*)dtT_f;
  unsigned short* xpwb_f = (unsigned short*)xpwb_f_;
  unsigned short* xpwb_r = (unsigned short*)xpwb_r_;
  unsigned short* dtwb_f = (unsigned short*)dtwb_f_;
  unsigned short* dtwb_r = (unsigned short*)dtwb_r_;

  float* outp = (float*)d_out;

  wconvert_kernel<<<3456, 256, 0, stream>>>(
      in_proj, out_w, xpw_f, xpw_r, dtw_f, dtw_r,
      wbfin, wbfout, xpwb_f, xpwb_r, dtwb_f, dtwb_r);

  for (int layer = 0; layer < 4; ++layer) {
    // layer input: previous layer's feats slot in d_out (or x for layer 0)
    const float* hsrc = layer == 0 ? x : (outp + (long)layer * 524288);
    addnorm_kernel<<<1024, 256, 0, stream>>>(
        hsrc, residual, norm_w + layer * DMODEL, nullptr, hnb, layer == 0 ? 1 : 0);
    gemm_in_kernel<<<dim3(16, 16), 256, 0, stream>>>(
        wbfin + (long)layer * 2048 * 512, hnb, xzbuf);
    conv_silu_kernel<<<dim3(32, 32, 2), 256, 0, stream>>>(
        xzbuf, convw_f + layer * DINNER * 4, convb_f + layer * DINNER,
        convw_r + layer * DINNER * 4, convb_r + layer * DINNER,
        xconv_f, xconv_r, xcT);
    xdbl_mfma_kernel<<<dim3(8, 2), 256, 0, stream>>>(
        xpwb_f + (long)layer * 64 * DINNER, xpwb_r + (long)layer * 64 * DINNER,
        xcT, dtT, xbc_f, xbc_r);
    deltam_kernel<<<dim3(8, 8, 2), 256, 0, stream>>>(
        dtwb_f + (long)layer * DINNER * DTRANK, dtwb_r + (long)layer * DINNER * DTRANK,
        dtT, dtb_f + layer * DINNER, dtb_r + layer * DINNER, delta_f, delta_r);
    scan_merged_kernel<<<512, 256, 0, stream>>>(
        delta_f, delta_r, xconv_f, xconv_r, xbc_f, xbc_r,
        Alog_f + layer * DINNER * DSTATE, Alog_r + layer * DINNER * DSTATE,
        Dsk_f + layer * DINNER, Dsk_r + layer * DINNER,
        xzbuf, ybuf);
    ytrans_kernel<<<dim3(32, 32), 256, 0, stream>>>(ybuf, ybt);
    gemm_out_kernel<<<dim3(8, 4), 256, 0, stream>>>(
        wbfout + (long)layer * 512 * 1024, ybt,
        outp + (long)(1 + layer) * 524288);
  }
  addnorm_kernel<<<1024, 256, 0, stream>>>(
      outp + 4 * 524288, residual, normf_w, outp, nullptr, 0);
}

// Round 13
// 389.921 us; speedup vs baseline: 1.1805x; 1.0006x over previous
//
#include <hip/hip_runtime.h>

#define BATCH 2
#define SEQ 512
#define DMODEL 512
#define DINNER 1024
#define DSTATE 16
#define DTRANK 32
#define NBL (BATCH*SEQ)      // 1024
#define EPSV 1e-5f

typedef __attribute__((ext_vector_type(8))) short bf16x8;
typedef __attribute__((ext_vector_type(4))) float f32x4;

static __device__ __forceinline__ float sigmoidf_(float x) {
  return 1.0f / (1.0f + __expf(-x));
}
static __device__ __forceinline__ float softplusf_(float x) {
  return fmaxf(x, 0.0f) + log1pf(__expf(-fabsf(x)));
}
static __device__ __forceinline__ unsigned short f2bf(float x) {
  unsigned int u = __float_as_uint(x);
  unsigned int r = (u + 0x7FFFu + ((u >> 16) & 1u)) >> 16;
  return (unsigned short)r;
}

// ---------------- all-weight fp32 -> bf16 convert (segmented) ----------------
__global__ __launch_bounds__(256) void wconvert_kernel(
    const float* __restrict__ s0, const float* __restrict__ s1,
    const float* __restrict__ s2, const float* __restrict__ s3,
    const float* __restrict__ s4, const float* __restrict__ s5,
    unsigned short* __restrict__ d0, unsigned short* __restrict__ d1,
    unsigned short* __restrict__ d2, unsigned short* __restrict__ d3,
    unsigned short* __restrict__ d4, unsigned short* __restrict__ d5) {
  long i = (long)(blockIdx.x * 256 + threadIdx.x) * 8;
  const float* src; unsigned short* dst;
  if (i < 4194304)      { src = s0; dst = d0; }
  else if (i < 6291456) { src = s1; dst = d1; i -= 4194304; }
  else if (i < 6553600) { src = s2; dst = d2; i -= 6291456; }
  else if (i < 6815744) { src = s3; dst = d3; i -= 6553600; }
  else if (i < 6946816) { src = s4; dst = d4; i -= 6815744; }
  else                  { src = s5; dst = d5; i -= 6946816; }
  const float4 v0 = *(const float4*)&src[i];
  const float4 v1 = *(const float4*)&src[i + 4];
  bf16x8 o;
  o[0] = (short)f2bf(v0.x); o[1] = (short)f2bf(v0.y);
  o[2] = (short)f2bf(v0.z); o[3] = (short)f2bf(v0.w);
  o[4] = (short)f2bf(v1.x); o[5] = (short)f2bf(v1.y);
  o[6] = (short)f2bf(v1.z); o[7] = (short)f2bf(v1.w);
  *(bf16x8*)&dst[i] = o;
}

// ---------------- fused add + RMSNorm ----------------
__global__ __launch_bounds__(256) void addnorm_kernel(
    const float* __restrict__ hs, float* __restrict__ residual,
    const float* __restrict__ w, float* __restrict__ out,
    unsigned short* __restrict__ outb, int first) {
  const int row = blockIdx.x;
  const int t = threadIdx.x;
  const float* hp = hs + (long)row * DMODEL;
  float* rp = residual + (long)row * DMODEL;
  float r0 = hp[t], r1 = hp[t + 256];
  if (!first) { r0 += rp[t]; r1 += rp[t + 256]; }
  rp[t] = r0; rp[t + 256] = r1;
  float ss = r0 * r0 + r1 * r1;
  #pragma unroll
  for (int off = 32; off; off >>= 1) ss += __shfl_xor(ss, off, 64);
  __shared__ float sw[4];
  const int wid = t >> 6, lane = t & 63;
  if (lane == 0) sw[wid] = ss;
  __syncthreads();
  const float tot = sw[0] + sw[1] + sw[2] + sw[3];
  const float scale = rsqrtf(tot * (1.0f / (float)DMODEL) + EPSV);
  const float v0 = r0 * scale * w[t];
  const float v1 = r1 * scale * w[t + 256];
  if (out) {
    out[(long)row * DMODEL + t] = v0;
    out[(long)row * DMODEL + t + 256] = v1;
  }
  if (outb) {
    outb[(long)row * DMODEL + t] = f2bf(v0);
    outb[(long)row * DMODEL + t + 256] = f2bf(v1);
  }
}

#define LDK 40
#define LDK2 72

// ---------------- in_proj GEMM: 128M x 64N, BK=64, reg-prefetch -------------
__global__ __launch_bounds__(256) void gemm_in_kernel(
    const unsigned short* __restrict__ A, const unsigned short* __restrict__ B,
    float* __restrict__ C) {
  __shared__ unsigned short As[128 * LDK2];
  __shared__ unsigned short Bs[64 * LDK2];
  const int t = threadIdx.x;
  const int m0 = blockIdx.y * 128, n0 = blockIdx.x * 64;
  const int lane = t & 63;
  const int w = t >> 6;
  const int wr = (w >> 1) * 64, wc = (w & 1) * 32;
  const int fr = lane & 15;
  const int fq = lane >> 4;
  const int K = DMODEL;

  f32x4 acc[4][2];
  #pragma unroll
  for (int i = 0; i < 4; ++i)
    #pragma unroll
    for (int j = 0; j < 2; ++j) {
      f32x4 z = {0.f, 0.f, 0.f, 0.f};
      acc[i][j] = z;
    }

  const int arow = t >> 1, ako = (t & 1) * 32;   // A: 128 x 64
  const int brow = t >> 2, bko = (t & 3) * 16;   // B: 64 x 64

  bf16x8 pa[4], pb[2];
  #define LOADG_IN(k0_) do {                                              \
    const unsigned short* ap = &A[(long)(m0 + arow) * K + (k0_) + ako];   \
    pa[0] = *(const bf16x8*)ap;        pa[1] = *(const bf16x8*)(ap + 8);  \
    pa[2] = *(const bf16x8*)(ap + 16); pa[3] = *(const bf16x8*)(ap + 24); \
    const unsigned short* bp = &B[(long)(n0 + brow) * K + (k0_) + bko];   \
    pb[0] = *(const bf16x8*)bp;        pb[1] = *(const bf16x8*)(bp + 8);  \
  } while (0)

  LOADG_IN(0);
  for (int k0 = 0; k0 < K; k0 += 64) {
    if (k0) __syncthreads();
    *(bf16x8*)&As[arow * LDK2 + ako]      = pa[0];
    *(bf16x8*)&As[arow * LDK2 + ako + 8]  = pa[1];
    *(bf16x8*)&As[arow * LDK2 + ako + 16] = pa[2];
    *(bf16x8*)&As[arow * LDK2 + ako + 24] = pa[3];
    *(bf16x8*)&Bs[brow * LDK2 + bko]      = pb[0];
    *(bf16x8*)&Bs[brow * LDK2 + bko + 8]  = pb[1];
    __syncthreads();
    if (k0 + 64 < K) LOADG_IN(k0 + 64);
    #pragma unroll
    for (int h = 0; h < 2; ++h) {
      bf16x8 af[4], bg[2];
      #pragma unroll
      for (int i = 0; i < 4; ++i)
        af[i] = *(const bf16x8*)&As[(wr + i * 16 + fr) * LDK2 + h * 32 + fq * 8];
      #pragma unroll
      for (int j = 0; j < 2; ++j)
        bg[j] = *(const bf16x8*)&Bs[(wc + j * 16 + fr) * LDK2 + h * 32 + fq * 8];
      #pragma unroll
      for (int i = 0; i < 4; ++i)
        #pragma unroll
        for (int j = 0; j < 2; ++j)
          acc[i][j] = __builtin_amdgcn_mfma_f32_16x16x32_bf16(
              af[i], bg[j], acc[i][j], 0, 0, 0);
    }
  }
  #undef LOADG_IN

  #pragma unroll
  for (int i = 0; i < 4; ++i)
    #pragma unroll
    for (int j = 0; j < 2; ++j)
      #pragma unroll
      for (int r2 = 0; r2 < 4; ++r2) {
        const int m = m0 + wr + i * 16 + fq * 4 + r2;
        const int n = n0 + wc + j * 16 + fr;
        C[(long)m * NBL + n] = acc[i][j][r2];
      }
}

// ---------------- conv+SiLU -> transposed bf16 xcT only ----------------
__global__ __launch_bounds__(256) void conv_silu_kernel(
    const float* __restrict__ xz,
    const float* __restrict__ cw_f, const float* __restrict__ cb_f,
    const float* __restrict__ cw_r, const float* __restrict__ cb_r,
    unsigned short* __restrict__ xcT) {
  __shared__ unsigned short tile[32][33];
  const int dir = blockIdx.z;
  const int n0 = blockIdx.x * 32, d0 = blockIdx.y * 32;
  const int b = n0 >> 9;
  const int l0 = n0 & (SEQ - 1);
  const float* cw = dir ? cw_r : cw_f;
  const float* cb = dir ? cb_r : cb_f;
  unsigned short* dst = xcT + (long)dir * DINNER * NBL;
  const int t = threadIdx.x;
  const int c = t & 31, rr = t >> 5;
  #pragma unroll
  for (int p = 0; p < 4; ++p) {
    const int d = d0 + p * 8 + rr;
    const int l = l0 + c;
    const float* xi = xz + (long)d * NBL + b * SEQ;
    float sum = cb[d];
    #pragma unroll
    for (int k = 0; k < 4; ++k) {
      const int tt = l - 3 + k;
      if (tt >= 0) {
        const int src = dir ? (SEQ - 1 - tt) : tt;
        sum += cw[d * 4 + k] * xi[src];
      }
    }
    const float v = sum * sigmoidf_(sum);
    tile[p * 8 + rr][c] = f2bf(v);
  }
  __syncthreads();
  #pragma unroll
  for (int p = 0; p < 4; ++p) {
    const int n = n0 + p * 8 + rr;
    dst[(long)n * DINNER + d0 + c] = tile[c][p * 8 + rr];
  }
}

// ---------------- x_dbl via MFMA: 64M x 128N, BK=64, reg-prefetch -----------
// rows<32 -> dtT bf16 (dir,n,32); rows>=32 -> xbcT fp32 [slot][NBL].
__global__ __launch_bounds__(256) void xdbl_mfma_kernel(
    const unsigned short* __restrict__ xpwb_f, const unsigned short* __restrict__ xpwb_r,
    const unsigned short* __restrict__ xcT,
    unsigned short* __restrict__ dtT,
    float* __restrict__ xbc_f, float* __restrict__ xbc_r) {
  __shared__ unsigned short As[64 * LDK2];
  __shared__ unsigned short Bs[128 * LDK2];
  const int t = threadIdx.x;
  const int dir = blockIdx.y;
  const int n0 = blockIdx.x * 128;
  const unsigned short* A = dir ? xpwb_r : xpwb_f;
  const unsigned short* B = xcT + (long)dir * DINNER * NBL;
  float* xbc = dir ? xbc_r : xbc_f;
  unsigned short* dtt = dtT + (long)dir * NBL * DTRANK;

  const int lane = t & 63;
  const int w = t >> 6;
  const int fr = lane & 15;
  const int fq = lane >> 4;

  f32x4 acc[4][2];
  #pragma unroll
  for (int i = 0; i < 4; ++i)
    #pragma unroll
    for (int j = 0; j < 2; ++j) {
      f32x4 z = {0.f, 0.f, 0.f, 0.f};
      acc[i][j] = z;
    }

  const int arow = t >> 2, ako = (t & 3) * 16;   // A: 64 x 64
  const int brow = t >> 1, bko = (t & 1) * 32;   // B: 128 x 64

  bf16x8 pa[2], pb[4];
  #define LOADG_XD(k0_) do {                                                   \
    const unsigned short* ap = &A[(long)arow * DINNER + (k0_) + ako];          \
    pa[0] = *(const bf16x8*)ap;        pa[1] = *(const bf16x8*)(ap + 8);       \
    const unsigned short* bp = &B[(long)(n0 + brow) * DINNER + (k0_) + bko];   \
    pb[0] = *(const bf16x8*)bp;        pb[1] = *(const bf16x8*)(bp + 8);       \
    pb[2] = *(const bf16x8*)(bp + 16); pb[3] = *(const bf16x8*)(bp + 24);      \
  } while (0)

  LOADG_XD(0);
  for (int k0 = 0; k0 < DINNER; k0 += 64) {
    if (k0) __syncthreads();
    *(bf16x8*)&As[arow * LDK2 + ako]      = pa[0];
    *(bf16x8*)&As[arow * LDK2 + ako + 8]  = pa[1];
    *(bf16x8*)&Bs[brow * LDK2 + bko]      = pb[0];
    *(bf16x8*)&Bs[brow * LDK2 + bko + 8]  = pb[1];
    *(bf16x8*)&Bs[brow * LDK2 + bko + 16] = pb[2];
    *(bf16x8*)&Bs[brow * LDK2 + bko + 24] = pb[3];
    __syncthreads();
    if (k0 + 64 < DINNER) LOADG_XD(k0 + 64);
    #pragma unroll
    for (int h = 0; h < 2; ++h) {
      bf16x8 af[4], bg[2];
      #pragma unroll
      for (int i = 0; i < 4; ++i)
        af[i] = *(const bf16x8*)&As[(i * 16 + fr) * LDK2 + h * 32 + fq * 8];
      #pragma unroll
      for (int j = 0; j < 2; ++j)
        bg[j] = *(const bf16x8*)&Bs[(w * 32 + j * 16 + fr) * LDK2 + h * 32 + fq * 8];
      #pragma unroll
      for (int i = 0; i < 4; ++i)
        #pragma unroll
        for (int j = 0; j < 2; ++j)
          acc[i][j] = __builtin_amdgcn_mfma_f32_16x16x32_bf16(
              af[i], bg[j], acc[i][j], 0, 0, 0);
    }
  }
  #undef LOADG_XD

  #pragma unroll
  for (int i = 0; i < 4; ++i)
    #pragma unroll
    for (int j = 0; j < 2; ++j)
      #pragma unroll
      for (int r2 = 0; r2 < 4; ++r2) {
        const int m = i * 16 + fq * 4 + r2;
        const int n = n0 + w * 32 + j * 16 + fr;
        const float v = acc[i][j][r2];
        if (m < DTRANK) dtt[(long)n * DTRANK + m] = f2bf(v);
        else xbc[(long)(m - 32) * NBL + n] = v;   // slot-major
      }
}

// ---------------- delta via MFMA: softplus(dtw @ dt + dtb) ----------------
__global__ __launch_bounds__(256) void deltam_kernel(
    const unsigned short* __restrict__ dtwb_f, const unsigned short* __restrict__ dtwb_r,
    const unsigned short* __restrict__ dtT,
    const float* __restrict__ dtb_f, const float* __restrict__ dtb_r,
    float* __restrict__ delta_f, float* __restrict__ delta_r) {
  __shared__ unsigned short As[128 * LDK];
  __shared__ unsigned short Bs[128 * LDK];
  const int t = threadIdx.x;
  const int dir = blockIdx.z;
  const unsigned short* A = dir ? dtwb_r : dtwb_f;
  const unsigned short* B = dtT + (long)dir * NBL * DTRANK;
  const float* dtb = dir ? dtb_r : dtb_f;
  float* dl = dir ? delta_r : delta_f;
  const int m0 = blockIdx.y * 128, n0 = blockIdx.x * 128;
  const int lane = t & 63;
  const int w = t >> 6;
  const int wr = (w >> 1) * 64, wc = (w & 1) * 64;
  const int fr = lane & 15;
  const int fq = lane >> 4;

  const int srow = t >> 1;
  const int sko = (t & 1) * 16;
  *(bf16x8*)&As[srow * LDK + sko] =
      *(const bf16x8*)&A[(long)(m0 + srow) * DTRANK + sko];
  *(bf16x8*)&As[srow * LDK + sko + 8] =
      *(const bf16x8*)&A[(long)(m0 + srow) * DTRANK + sko + 8];
  *(bf16x8*)&Bs[srow * LDK + sko] =
      *(const bf16x8*)&B[(long)(n0 + srow) * DTRANK + sko];
  *(bf16x8*)&Bs[srow * LDK + sko + 8] =
      *(const bf16x8*)&B[(long)(n0 + srow) * DTRANK + sko + 8];
  __syncthreads();

  bf16x8 af[4], bg[4];
  #pragma unroll
  for (int i = 0; i < 4; ++i) {
    af[i] = *(const bf16x8*)&As[(wr + i * 16 + fr) * LDK + fq * 8];
    bg[i] = *(const bf16x8*)&Bs[(wc + i * 16 + fr) * LDK + fq * 8];
  }
  f32x4 acc[4][4];
  #pragma unroll
  for (int i = 0; i < 4; ++i)
    #pragma unroll
    for (int j = 0; j < 4; ++j) {
      f32x4 z = {0.f, 0.f, 0.f, 0.f};
      acc[i][j] = __builtin_amdgcn_mfma_f32_16x16x32_bf16(af[i], bg[j], z, 0, 0, 0);
    }

  #pragma unroll
  for (int i = 0; i < 4; ++i) {
    const int m = m0 + wr + i * 16 + fq * 4;
    #pragma unroll
    for (int r2 = 0; r2 < 4; ++r2) {
      const float bias = dtb[m + r2];
      #pragma unroll
      for (int j = 0; j < 4; ++j) {
        const int n = n0 + wc + j * 16 + fr;
        dl[(long)(m + r2) * NBL + n] = softplusf_(acc[i][j][r2] + bias);
      }
    }
  }
}

// ---------------- fused conv+scan+gate+transpose ----------------
// 512 blocks x 4 waves; wave = one (b,d) row, both directions; conv computed
// in-register from xz (fwd + wave-mirrored reverse); output written directly
// to ybt bf16 (n,e) via LDS gather (absorbs ytrans).
static __device__ __forceinline__ void scan_pass(
    const float* __restrict__ dp, const float u[8],
    const float* __restrict__ bct, const float* __restrict__ Alog,
    float Dv, int lane, float out[8]) {
  float dt[8], dtu[8];
  {
    const float4 a0 = *(const float4*)&dp[0];
    const float4 a1 = *(const float4*)&dp[4];
    dt[0] = a0.x; dt[1] = a0.y; dt[2] = a0.z; dt[3] = a0.w;
    dt[4] = a1.x; dt[5] = a1.y; dt[6] = a1.z; dt[7] = a1.w;
  }
  #pragma unroll
  for (int j = 0; j < 8; ++j) { dtu[j] = dt[j] * u[j]; out[j] = 0.f; }

  for (int n = 0; n < DSTATE; ++n) {
    const float An = -__expf(Alog[n]);
    float Bv[8], Cv[8], dA[8], cB[8];
    {
      const float* bp = bct + (long)n * NBL;
      const float* cp = bct + (long)(DSTATE + n) * NBL;
      const float4 b0 = *(const float4*)&bp[0];
      const float4 b1 = *(const float4*)&bp[4];
      Bv[0] = b0.x; Bv[1] = b0.y; Bv[2] = b0.z; Bv[3] = b0.w;
      Bv[4] = b1.x; Bv[5] = b1.y; Bv[6] = b1.z; Bv[7] = b1.w;
      const float4 c0 = *(const float4*)&cp[0];
      const float4 c1 = *(const float4*)&cp[4];
      Cv[0] = c0.x; Cv[1] = c0.y; Cv[2] = c0.z; Cv[3] = c0.w;
      Cv[4] = c1.x; Cv[5] = c1.y; Cv[6] = c1.z; Cv[7] = c1.w;
    }
    float h = 0.f, P = 1.f;
    #pragma unroll
    for (int j = 0; j < 8; ++j) {
      dA[j] = __expf(dt[j] * An);
      cB[j] = dtu[j] * Bv[j];
      h = fmaf(h, dA[j], cB[j]);
      P *= dA[j];
    }
    float hs = h, Ps = P;
    #pragma unroll
    for (int off = 1; off < 64; off <<= 1) {
      const float hp = __shfl_up(hs, off, 64);
      const float Pp = __shfl_up(Ps, off, 64);
      if (lane >= off) { hs = fmaf(hp, Ps, hs); Ps *= Pp; }
    }
    float h0 = __shfl_up(hs, 1, 64);
    if (lane == 0) h0 = 0.f;
    #pragma unroll
    for (int j = 0; j < 8; ++j) {
      h0 = fmaf(h0, dA[j], cB[j]);
      out[j] = fmaf(h0, Cv[j], out[j]);
    }
  }
  #pragma unroll
  for (int j = 0; j < 8; ++j) out[j] = fmaf(Dv, u[j], out[j]);
}

__global__ __launch_bounds__(256) void scan_merged_kernel(
    const float* __restrict__ delta_f, const float* __restrict__ delta_r,
    const float* __restrict__ xbc_f, const float* __restrict__ xbc_r,
    const float* __restrict__ Alog_f, const float* __restrict__ Alog_r,
    const float* __restrict__ Dsk_f, const float* __restrict__ Dsk_r,
    const float* __restrict__ cw_f, const float* __restrict__ cb_f,
    const float* __restrict__ cw_r, const float* __restrict__ cb_r,
    const float* __restrict__ xz, unsigned short* __restrict__ ybt) {
  __shared__ unsigned short s_t[4][512];
  const int t = threadIdx.x;
  const int wv = t >> 6;
  const int lane = t & 63;
  const int row = blockIdx.x * 4 + wv;          // 0..2047
  const int b = row >> 10, d = row & 1023;
  const long rbase = (long)d * NBL + b * SEQ;

  // ---- load x row (8 steps/lane) ----
  float xv[8];
  {
    const float* xp = xz + rbase + lane * 8;
    const float4 a0 = *(const float4*)&xp[0];
    const float4 a1 = *(const float4*)&xp[4];
    xv[0] = a0.x; xv[1] = a0.y; xv[2] = a0.z; xv[3] = a0.w;
    xv[4] = a1.x; xv[5] = a1.y; xv[6] = a1.z; xv[7] = a1.w;
  }
  // ---- forward conv + silu -> uf ----
  float uf[8];
  {
    float cw0 = cw_f[d * 4], cw1 = cw_f[d * 4 + 1], cw2 = cw_f[d * 4 + 2],
          cw3 = cw_f[d * 4 + 3], cb = cb_f[d];
    float xm1 = __shfl_up(xv[7], 1, 64);
    float xm2 = __shfl_up(xv[6], 1, 64);
    float xm3 = __shfl_up(xv[5], 1, 64);
    const float ext[3] = {xm3, xm2, xm1};  // x[p-3],x[p-2],x[p-1] for j=0
    #pragma unroll
    for (int j = 0; j < 8; ++j) {
      float s = cb + cw3 * xv[j];
      const int p = lane * 8 + j;
      // k=0..2 -> x[p-3+k]
      #pragma unroll
      for (int k = 0; k < 3; ++k) {
        const int idx = j - 3 + k;
        const float xval = (idx >= 0) ? xv[idx] : ext[3 + idx];
        if (p - 3 + k >= 0) s += (k == 0 ? cw0 : (k == 1 ? cw1 : cw2)) * xval;
      }
      uf[j] = s * sigmoidf_(s);
    }
  }
  // ---- mirrored x for reverse conv ----
  float xr[8];
  #pragma unroll
  for (int j = 0; j < 8; ++j) xr[j] = __shfl(xv[7 - j], 63 - lane, 64);
  float ur[8];
  {
    float cw0 = cw_r[d * 4], cw1 = cw_r[d * 4 + 1], cw2 = cw_r[d * 4 + 2],
          cw3 = cw_r[d * 4 + 3], cb = cb_r[d];
    float xm1 = __shfl_up(xr[7], 1, 64);
    float xm2 = __shfl_up(xr[6], 1, 64);
    float xm3 = __shfl_up(xr[5], 1, 64);
    const float ext[3] = {xm3, xm2, xm1};
    #pragma unroll
    for (int j = 0; j < 8; ++j) {
      float s = cb + cw3 * xr[j];
      const int p = lane * 8 + j;
      #pragma unroll
      for (int k = 0; k < 3; ++k) {
        const int idx = j - 3 + k;
        const float xval = (idx >= 0) ? xr[idx] : ext[3 + idx];
        if (p - 3 + k >= 0) s += (k == 0 ? cw0 : (k == 1 ? cw1 : cw2)) * xval;
      }
      ur[j] = s * sigmoidf_(s);
    }
  }

  float af[8], ar[8];
  scan_pass(delta_f + rbase + lane * 8, uf,
            xbc_f + b * SEQ + lane * 8, Alog_f + d * DSTATE, Dsk_f[d], lane, af);
  scan_pass(delta_r + rbase + lane * 8, ur,
            xbc_r + b * SEQ + lane * 8, Alog_r + d * DSTATE, Dsk_r[d], lane, ar);

  // ---- gate + mirror reverse into forward order ----
  const float* zp = xz + (long)(DINNER + d) * NBL + b * SEQ + lane * 8;
  const float4 z0 = *(const float4*)&zp[0];
  const float4 z1 = *(const float4*)&zp[4];
  const float zv[8] = {z0.x, z0.y, z0.z, z0.w, z1.x, z1.y, z1.z, z1.w};
  bf16x8 obf;
  #pragma unroll
  for (int j = 0; j < 8; ++j) {
    const float v = __shfl(ar[7 - j], 63 - lane, 64);
    obf[j] = (short)f2bf((af[j] + v) * (zv[j] * sigmoidf_(zv[j])));
  }
  // ---- stage per-wave, then block writes ybt (n, e) bf16 ----
  *(bf16x8*)&s_t[wv][lane * 8] = obf;
  __syncthreads();
  const int d0 = (blockIdx.x * 4) & 1023;
  const int bb = (blockIdx.x * 4) >> 10;
  unsigned short* yrow = ybt + (long)(bb * SEQ) * DINNER + d0;
  #pragma unroll
  for (int q = 0; q < 2; ++q) {
    const int n = t * 2 + q;
    ushort4 v = {s_t[0][n], s_t[1][n], s_t[2][n], s_t[3][n]};
    *(ushort4*)&yrow[(long)n * DINNER] = v;
  }
}

// ---------------- out_proj GEMM: 128x128, BK=64, reg-prefetch ---------------
__global__ __launch_bounds__(256) void gemm_out_kernel(
    const unsigned short* __restrict__ A, const unsigned short* __restrict__ B,
    float* __restrict__ C) {
  __shared__ unsigned short As[128 * LDK2];
  __shared__ unsigned short Bs[128 * LDK2];
  const int t = threadIdx.x;
  const int m0 = blockIdx.y * 128, n0 = blockIdx.x * 128;
  const int lane = t & 63;
  const int w = t >> 6;
  const int wr = (w >> 1) * 64, wc = (w & 1) * 64;
  const int fr = lane & 15;
  const int fq = lane >> 4;
  const int K = DINNER;

  f32x4 acc[4][4];
  #pragma unroll
  for (int i = 0; i < 4; ++i)
    #pragma unroll
    for (int j = 0; j < 4; ++j) {
      f32x4 z = {0.f, 0.f, 0.f, 0.f};
      acc[i][j] = z;
    }

  const int srow = t >> 1, sko = (t & 1) * 32;

  bf16x8 pa[4], pb[4];
  #define LOADG_OUT(k0_) do {                                              \
    const unsigned short* ap = &A[(long)(m0 + srow) * K + (k0_) + sko];    \
    pa[0] = *(const bf16x8*)ap;        pa[1] = *(const bf16x8*)(ap + 8);   \
    pa[2] = *(const bf16x8*)(ap + 16); pa[3] = *(const bf16x8*)(ap + 24);  \
    const unsigned short* bp = &B[(long)(n0 + srow) * K + (k0_) + sko];    \
    pb[0] = *(const bf16x8*)bp;        pb[1] = *(const bf16x8*)(bp + 8);   \
    pb[2] = *(const bf16x8*)(bp + 16); pb[3] = *(const bf16x8*)(bp + 24);  \
  } while (0)

  LOADG_OUT(0);
  for (int k0 = 0; k0 < K; k0 += 64) {
    if (k0) __syncthreads();
    *(bf16x8*)&As[srow * LDK2 + sko]      = pa[0];
    *(bf16x8*)&As[srow * LDK2 + sko + 8]  = pa[1];
    *(bf16x8*)&As[srow * LDK2 + sko + 16] = pa[2];
    *(bf16x8*)&As[srow * LDK2 + sko + 24] = pa[3];
    *(bf16x8*)&Bs[srow * LDK2 + sko]      = pb[0];
    *(bf16x8*)&Bs[srow * LDK2 + sko + 8]  = pb[1];
    *(bf16x8*)&Bs[srow * LDK2 + sko + 16] = pb[2];
    *(bf16x8*)&Bs[srow * LDK2 + sko + 24] = pb[3];
    __syncthreads();
    if (k0 + 64 < K) LOADG_OUT(k0 + 64);
    #pragma unroll
    for (int h = 0; h < 2; ++h) {
      bf16x8 af[4], bg[4];
      #pragma unroll
      for (int i = 0; i < 4; ++i) {
        af[i] = *(const bf16x8*)&As[(wr + i * 16 + fr) * LDK2 + h * 32 + fq * 8];
        bg[i] = *(const bf16x8*)&Bs[(wc + i * 16 + fr) * LDK2 + h * 32 + fq * 8];
      }
      #pragma unroll
      for (int i = 0; i < 4; ++i)
        #pragma unroll
        for (int j = 0; j < 4; ++j)
          acc[i][j] = __builtin_amdgcn_mfma_f32_16x16x32_bf16(
              af[i], bg[j], acc[i][j], 0, 0, 0);
    }
  }
  #undef LOADG_OUT

  #pragma unroll
  for (int i = 0; i < 4; ++i)
    #pragma unroll
    for (int j = 0; j < 4; ++j)
      #pragma unroll
      for (int r2 = 0; r2 < 4; ++r2) {
        const int m = m0 + wr + i * 16 + fq * 4 + r2;
        const int n = n0 + wc + j * 16 + fr;
        C[(long)n * DMODEL + m] = acc[i][j][r2];
      }
}

extern "C" void kernel_launch(void* const* d_in, const int* in_sizes, int n_in,
                              void* d_out, int out_size, void* d_ws, size_t ws_size,
                              hipStream_t stream) {
  (void)in_sizes; (void)n_in; (void)out_size; (void)ws_size;
  const float* x       = (const float*)d_in[0];
  const float* norm_w  = (const float*)d_in[1];
  const float* in_proj = (const float*)d_in[2];
  const float* convw_f = (const float*)d_in[3];
  const float* convb_f = (const float*)d_in[4];
  const float* xpw_f   = (const float*)d_in[5];
  const float* dtw_f   = (const float*)d_in[6];
  const float* dtb_f   = (const float*)d_in[7];
  const float* Alog_f  = (const float*)d_in[8];
  const float* Dsk_f   = (const float*)d_in[9];
  const float* convw_r = (const float*)d_in[10];
  const float* convb_r = (const float*)d_in[11];
  const float* xpw_r   = (const float*)d_in[12];
  const float* dtw_r   = (const float*)d_in[13];
  const float* dtb_r   = (const float*)d_in[14];
  const float* Alog_r  = (const float*)d_in[15];
  const float* Dsk_r   = (const float*)d_in[16];
  const float* out_w   = (const float*)d_in[17];
  const float* normf_w = (const float*)d_in[18];

  float* ws = (float*)d_ws;
  float* residual = ws;  ws += 524288;
  float* xzbuf    = ws;  ws += 2097152;
  float* xbc_f    = ws;  ws += 32768;
  float* xbc_r    = ws;  ws += 32768;
  float* delta_f  = ws;  ws += 1048576;
  float* delta_r  = ws;  ws += 1048576;
  float* hnb_f    = ws;  ws += 262144;   // 1024x512 bf16
  float* wbfin_f  = ws;  ws += 2097152;  // 4x2048x512 bf16
  float* wbfout_f = ws;  ws += 1048576;  // 4x512x1024 bf16
  float* ybt_f    = ws;  ws += 524288;   // 1024x1024 bf16
  float* xcT_f    = ws;  ws += 1048576;  // 2 x 1024 x 1024 bf16
  float* dtT_f    = ws;  ws += 32768;    // 2 x 1024 x 32 bf16
  float* xpwb_f_  = ws;  ws += 131072;
  float* xpwb_r_  = ws;  ws += 131072;
  float* dtwb_f_  = ws;  ws += 65536;
  float* dtwb_r_  = ws;  ws += 65536;

  unsigned short* hnb = (unsigned short*)hnb_f;
  unsigned short* wbfin = (unsigned short*)wbfin_f;
  unsigned short* wbfout = (unsigned short*)wbfout_f;
  unsigned short* ybt = (unsigned short*)ybt_f;
  unsigned short* xcT = (unsigned short*)xcT_f;
  unsigned short* dtT = (unsigned short*)dtT_f;
  unsigned short* xpwb_f = (unsigned short*)xpwb_f_;
  unsigned short* xpwb_r = (unsigned short*)xpwb_r_;
  unsigned short* dtwb_f = (unsigned short*)dtwb_f_;
  unsigned short* dtwb_r = (unsigned short*)dtwb_r_;

  float* outp = (float*)d_out;

  wconvert_kernel<<<3456, 256, 0, stream>>>(
      in_proj, out_w, xpw_f, xpw_r, dtw_f, dtw_r,
      wbfin, wbfout, xpwb_f, xpwb_r, dtwb_f, dtwb_r);

  for (int layer = 0; layer < 4; ++layer) {
    const float* hsrc = layer == 0 ? x : (outp + (long)layer * 524288);
    addnorm_kernel<<<1024, 256, 0, stream>>>(
        hsrc, residual, norm_w + layer * DMODEL, nullptr, hnb, layer == 0 ? 1 : 0);
    gemm_in_kernel<<<dim3(16, 16), 256, 0, stream>>>(
        wbfin + (long)layer * 2048 * 512, hnb, xzbuf);
    conv_silu_kernel<<<dim3(32, 32, 2), 256, 0, stream>>>(
        xzbuf, convw_f + layer * DINNER * 4, convb_f + layer * DINNER,
        convw_r + layer * DINNER * 4, convb_r + layer * DINNER, xcT);
    xdbl_mfma_kernel<<<dim3(8, 2), 256, 0, stream>>>(
        xpwb_f + (long)layer * 64 * DINNER, xpwb_r + (long)layer * 64 * DINNER,
        xcT, dtT, xbc_f, xbc_r);
    deltam_kernel<<<dim3(8, 8, 2), 256, 0, stream>>>(
        dtwb_f + (long)layer * DINNER * DTRANK, dtwb_r + (long)layer * DINNER * DTRANK,
        dtT, dtb_f + layer * DINNER, dtb_r + layer * DINNER, delta_f, delta_r);
    scan_merged_kernel<<<512, 256, 0, stream>>>(
        delta_f, delta_r, xbc_f, xbc_r,
        Alog_f + layer * DINNER * DSTATE, Alog_r + layer * DINNER * DSTATE,
        Dsk_f + layer * DINNER, Dsk_r + layer * DINNER,
        convw_f + layer * DINNER * 4, convb_f + layer * DINNER,
        convw_r + layer * DINNER * 4, convb_r + layer * DINNER,
        xzbuf, ybt);
    gemm_out_kernel<<<dim3(8, 4), 256, 0, stream>>>(
        wbfout + (long)layer * 512 * 1024, ybt,
        outp + (long)(1 + layer) * 524288);
  }
  addnorm_kernel<<<1024, 256, 0, stream>>>(
      outp + 4 * 524288, residual, normf_w, outp, nullptr, 0);
}

// Round 14
// 366.683 us; speedup vs baseline: 1.2553x; 1.0634x over previous
//
#include <hip/hip_runtime.h>

#define BATCH 2
#define SEQ 512
#define DMODEL 512
#define DINNER 1024
#define DSTATE 16
#define DTRANK 32
#define NBL (BATCH*SEQ)      // 1024
#define EPSV 1e-5f

typedef __attribute__((ext_vector_type(8))) short bf16x8;
typedef __attribute__((ext_vector_type(4))) float f32x4;

static __device__ __forceinline__ float sigmoidf_(float x) {
  return 1.0f / (1.0f + __expf(-x));
}
static __device__ __forceinline__ float softplusf_(float x) {
  return fmaxf(x, 0.0f) + log1pf(__expf(-fabsf(x)));
}
static __device__ __forceinline__ unsigned short f2bf(float x) {
  unsigned int u = __float_as_uint(x);
  unsigned int r = (u + 0x7FFFu + ((u >> 16) & 1u)) >> 16;
  return (unsigned short)r;
}

// ---------------- all-weight fp32 -> bf16 convert (segmented) ----------------
__global__ __launch_bounds__(256) void wconvert_kernel(
    const float* __restrict__ s0, const float* __restrict__ s1,
    const float* __restrict__ s2, const float* __restrict__ s3,
    const float* __restrict__ s4, const float* __restrict__ s5,
    unsigned short* __restrict__ d0, unsigned short* __restrict__ d1,
    unsigned short* __restrict__ d2, unsigned short* __restrict__ d3,
    unsigned short* __restrict__ d4, unsigned short* __restrict__ d5) {
  long i = (long)(blockIdx.x * 256 + threadIdx.x) * 8;
  const float* src; unsigned short* dst;
  if (i < 4194304)      { src = s0; dst = d0; }
  else if (i < 6291456) { src = s1; dst = d1; i -= 4194304; }
  else if (i < 6553600) { src = s2; dst = d2; i -= 6291456; }
  else if (i < 6815744) { src = s3; dst = d3; i -= 6553600; }
  else if (i < 6946816) { src = s4; dst = d4; i -= 6815744; }
  else                  { src = s5; dst = d5; i -= 6946816; }
  const float4 v0 = *(const float4*)&src[i];
  const float4 v1 = *(const float4*)&src[i + 4];
  bf16x8 o;
  o[0] = (short)f2bf(v0.x); o[1] = (short)f2bf(v0.y);
  o[2] = (short)f2bf(v0.z); o[3] = (short)f2bf(v0.w);
  o[4] = (short)f2bf(v1.x); o[5] = (short)f2bf(v1.y);
  o[6] = (short)f2bf(v1.z); o[7] = (short)f2bf(v1.w);
  *(bf16x8*)&dst[i] = o;
}

// ---------------- fused add + RMSNorm ----------------
__global__ __launch_bounds__(256) void addnorm_kernel(
    const float* __restrict__ hs, float* __restrict__ residual,
    const float* __restrict__ w, float* __restrict__ out,
    unsigned short* __restrict__ outb, int first) {
  const int row = blockIdx.x;
  const int t = threadIdx.x;
  const float* hp = hs + (long)row * DMODEL;
  float* rp = residual + (long)row * DMODEL;
  float r0 = hp[t], r1 = hp[t + 256];
  if (!first) { r0 += rp[t]; r1 += rp[t + 256]; }
  rp[t] = r0; rp[t + 256] = r1;
  float ss = r0 * r0 + r1 * r1;
  #pragma unroll
  for (int off = 32; off; off >>= 1) ss += __shfl_xor(ss, off, 64);
  __shared__ float sw[4];
  const int wid = t >> 6, lane = t & 63;
  if (lane == 0) sw[wid] = ss;
  __syncthreads();
  const float tot = sw[0] + sw[1] + sw[2] + sw[3];
  const float scale = rsqrtf(tot * (1.0f / (float)DMODEL) + EPSV);
  const float v0 = r0 * scale * w[t];
  const float v1 = r1 * scale * w[t + 256];
  if (out) {
    out[(long)row * DMODEL + t] = v0;
    out[(long)row * DMODEL + t + 256] = v1;
  }
  if (outb) {
    outb[(long)row * DMODEL + t] = f2bf(v0);
    outb[(long)row * DMODEL + t + 256] = f2bf(v1);
  }
}

#define LDK 40
#define LDK2 72

// ---------------- in_proj GEMM: 128M x 64N, BK=64, reg-prefetch -------------
__global__ __launch_bounds__(256) void gemm_in_kernel(
    const unsigned short* __restrict__ A, const unsigned short* __restrict__ B,
    float* __restrict__ C) {
  __shared__ unsigned short As[128 * LDK2];
  __shared__ unsigned short Bs[64 * LDK2];
  const int t = threadIdx.x;
  const int m0 = blockIdx.y * 128, n0 = blockIdx.x * 64;
  const int lane = t & 63;
  const int w = t >> 6;
  const int wr = (w >> 1) * 64, wc = (w & 1) * 32;
  const int fr = lane & 15;
  const int fq = lane >> 4;
  const int K = DMODEL;

  f32x4 acc[4][2];
  #pragma unroll
  for (int i = 0; i < 4; ++i)
    #pragma unroll
    for (int j = 0; j < 2; ++j) {
      f32x4 z = {0.f, 0.f, 0.f, 0.f};
      acc[i][j] = z;
    }

  const int arow = t >> 1, ako = (t & 1) * 32;   // A: 128 x 64
  const int brow = t >> 2, bko = (t & 3) * 16;   // B: 64 x 64

  bf16x8 pa[4], pb[2];
  #define LOADG_IN(k0_) do {                                              \
    const unsigned short* ap = &A[(long)(m0 + arow) * K + (k0_) + ako];   \
    pa[0] = *(const bf16x8*)ap;        pa[1] = *(const bf16x8*)(ap + 8);  \
    pa[2] = *(const bf16x8*)(ap + 16); pa[3] = *(const bf16x8*)(ap + 24); \
    const unsigned short* bp = &B[(long)(n0 + brow) * K + (k0_) + bko];   \
    pb[0] = *(const bf16x8*)bp;        pb[1] = *(const bf16x8*)(bp + 8);  \
  } while (0)

  LOADG_IN(0);
  for (int k0 = 0; k0 < K; k0 += 64) {
    if (k0) __syncthreads();
    *(bf16x8*)&As[arow * LDK2 + ako]      = pa[0];
    *(bf16x8*)&As[arow * LDK2 + ako + 8]  = pa[1];
    *(bf16x8*)&As[arow * LDK2 + ako + 16] = pa[2];
    *(bf16x8*)&As[arow * LDK2 + ako + 24] = pa[3];
    *(bf16x8*)&Bs[brow * LDK2 + bko]      = pb[0];
    *(bf16x8*)&Bs[brow * LDK2 + bko + 8]  = pb[1];
    __syncthreads();
    if (k0 + 64 < K) LOADG_IN(k0 + 64);
    #pragma unroll
    for (int h = 0; h < 2; ++h) {
      bf16x8 af[4], bg[2];
      #pragma unroll
      for (int i = 0; i < 4; ++i)
        af[i] = *(const bf16x8*)&As[(wr + i * 16 + fr) * LDK2 + h * 32 + fq * 8];
      #pragma unroll
      for (int j = 0; j < 2; ++j)
        bg[j] = *(const bf16x8*)&Bs[(wc + j * 16 + fr) * LDK2 + h * 32 + fq * 8];
      #pragma unroll
      for (int i = 0; i < 4; ++i)
        #pragma unroll
        for (int j = 0; j < 2; ++j)
          acc[i][j] = __builtin_amdgcn_mfma_f32_16x16x32_bf16(
              af[i], bg[j], acc[i][j], 0, 0, 0);
    }
  }
  #undef LOADG_IN

  #pragma unroll
  for (int i = 0; i < 4; ++i)
    #pragma unroll
    for (int j = 0; j < 2; ++j)
      #pragma unroll
      for (int r2 = 0; r2 < 4; ++r2) {
        const int m = m0 + wr + i * 16 + fq * 4 + r2;
        const int n = n0 + wc + j * 16 + fr;
        C[(long)m * NBL + n] = acc[i][j][r2];
      }
}

// ---------------- conv+SiLU -> transposed bf16 xcT only ----------------
__global__ __launch_bounds__(256) void conv_silu_kernel(
    const float* __restrict__ xz,
    const float* __restrict__ cw_f, const float* __restrict__ cb_f,
    const float* __restrict__ cw_r, const float* __restrict__ cb_r,
    unsigned short* __restrict__ xcT) {
  __shared__ unsigned short tile[32][33];
  const int dir = blockIdx.z;
  const int n0 = blockIdx.x * 32, d0 = blockIdx.y * 32;
  const int b = n0 >> 9;
  const int l0 = n0 & (SEQ - 1);
  const float* cw = dir ? cw_r : cw_f;
  const float* cb = dir ? cb_r : cb_f;
  unsigned short* dst = xcT + (long)dir * DINNER * NBL;
  const int t = threadIdx.x;
  const int c = t & 31, rr = t >> 5;
  #pragma unroll
  for (int p = 0; p < 4; ++p) {
    const int d = d0 + p * 8 + rr;
    const int l = l0 + c;
    const float* xi = xz + (long)d * NBL + b * SEQ;
    float sum = cb[d];
    #pragma unroll
    for (int k = 0; k < 4; ++k) {
      const int tt = l - 3 + k;
      if (tt >= 0) {
        const int src = dir ? (SEQ - 1 - tt) : tt;
        sum += cw[d * 4 + k] * xi[src];
      }
    }
    const float v = sum * sigmoidf_(sum);
    tile[p * 8 + rr][c] = f2bf(v);
  }
  __syncthreads();
  #pragma unroll
  for (int p = 0; p < 4; ++p) {
    const int n = n0 + p * 8 + rr;
    dst[(long)n * DINNER + d0 + c] = tile[c][p * 8 + rr];
  }
}

// ---------------- x_dbl via MFMA: 64M x 128N, BK=64, reg-prefetch -----------
__global__ __launch_bounds__(256) void xdbl_mfma_kernel(
    const unsigned short* __restrict__ xpwb_f, const unsigned short* __restrict__ xpwb_r,
    const unsigned short* __restrict__ xcT,
    unsigned short* __restrict__ dtT,
    float* __restrict__ xbc_f, float* __restrict__ xbc_r) {
  __shared__ unsigned short As[64 * LDK2];
  __shared__ unsigned short Bs[128 * LDK2];
  const int t = threadIdx.x;
  const int dir = blockIdx.y;
  const int n0 = blockIdx.x * 128;
  const unsigned short* A = dir ? xpwb_r : xpwb_f;
  const unsigned short* B = xcT + (long)dir * DINNER * NBL;
  float* xbc = dir ? xbc_r : xbc_f;
  unsigned short* dtt = dtT + (long)dir * NBL * DTRANK;

  const int lane = t & 63;
  const int w = t >> 6;
  const int fr = lane & 15;
  const int fq = lane >> 4;

  f32x4 acc[4][2];
  #pragma unroll
  for (int i = 0; i < 4; ++i)
    #pragma unroll
    for (int j = 0; j < 2; ++j) {
      f32x4 z = {0.f, 0.f, 0.f, 0.f};
      acc[i][j] = z;
    }

  const int arow = t >> 2, ako = (t & 3) * 16;   // A: 64 x 64
  const int brow = t >> 1, bko = (t & 1) * 32;   // B: 128 x 64

  bf16x8 pa[2], pb[4];
  #define LOADG_XD(k0_) do {                                                   \
    const unsigned short* ap = &A[(long)arow * DINNER + (k0_) + ako];          \
    pa[0] = *(const bf16x8*)ap;        pa[1] = *(const bf16x8*)(ap + 8);       \
    const unsigned short* bp = &B[(long)(n0 + brow) * DINNER + (k0_) + bko];   \
    pb[0] = *(const bf16x8*)bp;        pb[1] = *(const bf16x8*)(bp + 8);       \
    pb[2] = *(const bf16x8*)(bp + 16); pb[3] = *(const bf16x8*)(bp + 24);      \
  } while (0)

  LOADG_XD(0);
  for (int k0 = 0; k0 < DINNER; k0 += 64) {
    if (k0) __syncthreads();
    *(bf16x8*)&As[arow * LDK2 + ako]      = pa[0];
    *(bf16x8*)&As[arow * LDK2 + ako + 8]  = pa[1];
    *(bf16x8*)&Bs[brow * LDK2 + bko]      = pb[0];
    *(bf16x8*)&Bs[brow * LDK2 + bko + 8]  = pb[1];
    *(bf16x8*)&Bs[brow * LDK2 + bko + 16] = pb[2];
    *(bf16x8*)&Bs[brow * LDK2 + bko + 24] = pb[3];
    __syncthreads();
    if (k0 + 64 < DINNER) LOADG_XD(k0 + 64);
    #pragma unroll
    for (int h = 0; h < 2; ++h) {
      bf16x8 af[4], bg[2];
      #pragma unroll
      for (int i = 0; i < 4; ++i)
        af[i] = *(const bf16x8*)&As[(i * 16 + fr) * LDK2 + h * 32 + fq * 8];
      #pragma unroll
      for (int j = 0; j < 2; ++j)
        bg[j] = *(const bf16x8*)&Bs[(w * 32 + j * 16 + fr) * LDK2 + h * 32 + fq * 8];
      #pragma unroll
      for (int i = 0; i < 4; ++i)
        #pragma unroll
        for (int j = 0; j < 2; ++j)
          acc[i][j] = __builtin_amdgcn_mfma_f32_16x16x32_bf16(
              af[i], bg[j], acc[i][j], 0, 0, 0);
    }
  }
  #undef LOADG_XD

  #pragma unroll
  for (int i = 0; i < 4; ++i)
    #pragma unroll
    for (int j = 0; j < 2; ++j)
      #pragma unroll
      for (int r2 = 0; r2 < 4; ++r2) {
        const int m = i * 16 + fq * 4 + r2;
        const int n = n0 + w * 32 + j * 16 + fr;
        const float v = acc[i][j][r2];
        if (m < DTRANK) dtt[(long)n * DTRANK + m] = f2bf(v);
        else xbc[(long)(m - 32) * NBL + n] = v;   // slot-major
      }
}

// ---------------- delta via MFMA: softplus(dtw @ dt + dtb) ----------------
__global__ __launch_bounds__(256) void deltam_kernel(
    const unsigned short* __restrict__ dtwb_f, const unsigned short* __restrict__ dtwb_r,
    const unsigned short* __restrict__ dtT,
    const float* __restrict__ dtb_f, const float* __restrict__ dtb_r,
    float* __restrict__ delta_f, float* __restrict__ delta_r) {
  __shared__ unsigned short As[128 * LDK];
  __shared__ unsigned short Bs[128 * LDK];
  const int t = threadIdx.x;
  const int dir = blockIdx.z;
  const unsigned short* A = dir ? dtwb_r : dtwb_f;
  const unsigned short* B = dtT + (long)dir * NBL * DTRANK;
  const float* dtb = dir ? dtb_r : dtb_f;
  float* dl = dir ? delta_r : delta_f;
  const int m0 = blockIdx.y * 128, n0 = blockIdx.x * 128;
  const int lane = t & 63;
  const int w = t >> 6;
  const int wr = (w >> 1) * 64, wc = (w & 1) * 64;
  const int fr = lane & 15;
  const int fq = lane >> 4;

  const int srow = t >> 1;
  const int sko = (t & 1) * 16;
  *(bf16x8*)&As[srow * LDK + sko] =
      *(const bf16x8*)&A[(long)(m0 + srow) * DTRANK + sko];
  *(bf16x8*)&As[srow * LDK + sko + 8] =
      *(const bf16x8*)&A[(long)(m0 + srow) * DTRANK + sko + 8];
  *(bf16x8*)&Bs[srow * LDK + sko] =
      *(const bf16x8*)&B[(long)(n0 + srow) * DTRANK + sko];
  *(bf16x8*)&Bs[srow * LDK + sko + 8] =
      *(const bf16x8*)&B[(long)(n0 + srow) * DTRANK + sko + 8];
  __syncthreads();

  bf16x8 af[4], bg[4];
  #pragma unroll
  for (int i = 0; i < 4; ++i) {
    af[i] = *(const bf16x8*)&As[(wr + i * 16 + fr) * LDK + fq * 8];
    bg[i] = *(const bf16x8*)&Bs[(wc + i * 16 + fr) * LDK + fq * 8];
  }
  f32x4 acc[4][4];
  #pragma unroll
  for (int i = 0; i < 4; ++i)
    #pragma unroll
    for (int j = 0; j < 4; ++j) {
      f32x4 z = {0.f, 0.f, 0.f, 0.f};
      acc[i][j] = __builtin_amdgcn_mfma_f32_16x16x32_bf16(af[i], bg[j], z, 0, 0, 0);
    }

  #pragma unroll
  for (int i = 0; i < 4; ++i) {
    const int m = m0 + wr + i * 16 + fq * 4;
    #pragma unroll
    for (int r2 = 0; r2 < 4; ++r2) {
      const float bias = dtb[m + r2];
      #pragma unroll
      for (int j = 0; j < 4; ++j) {
        const int n = n0 + wc + j * 16 + fr;
        dl[(long)(m + r2) * NBL + n] = softplusf_(acc[i][j][r2] + bias);
      }
    }
  }
}

// ---------------- fused conv+scan+gate+transpose, dir-split waves -----------
// 512 blocks x 8 waves (512 thr); wave = one (b,d,dir); 4 d-rows per block.
// Reverse waves mirror + park in LDS; forward waves add+gate+bf16; block
// gathers ushort4 into ybt (n,e).
static __device__ __forceinline__ void scan_pass(
    const float* __restrict__ dp, const float u[8],
    const float* __restrict__ bct, const float* __restrict__ Alog,
    float Dv, int lane, float out[8]) {
  float dt[8], dtu[8];
  {
    const float4 a0 = *(const float4*)&dp[0];
    const float4 a1 = *(const float4*)&dp[4];
    dt[0] = a0.x; dt[1] = a0.y; dt[2] = a0.z; dt[3] = a0.w;
    dt[4] = a1.x; dt[5] = a1.y; dt[6] = a1.z; dt[7] = a1.w;
  }
  #pragma unroll
  for (int j = 0; j < 8; ++j) { dtu[j] = dt[j] * u[j]; out[j] = 0.f; }

  for (int n = 0; n < DSTATE; ++n) {
    const float An = -__expf(Alog[n]);
    float Bv[8], Cv[8], dA[8], cB[8];
    {
      const float* bp = bct + (long)n * NBL;
      const float* cp = bct + (long)(DSTATE + n) * NBL;
      const float4 b0 = *(const float4*)&bp[0];
      const float4 b1 = *(const float4*)&bp[4];
      Bv[0] = b0.x; Bv[1] = b0.y; Bv[2] = b0.z; Bv[3] = b0.w;
      Bv[4] = b1.x; Bv[5] = b1.y; Bv[6] = b1.z; Bv[7] = b1.w;
      const float4 c0 = *(const float4*)&cp[0];
      const float4 c1 = *(const float4*)&cp[4];
      Cv[0] = c0.x; Cv[1] = c0.y; Cv[2] = c0.z; Cv[3] = c0.w;
      Cv[4] = c1.x; Cv[5] = c1.y; Cv[6] = c1.z; Cv[7] = c1.w;
    }
    float h = 0.f, P = 1.f;
    #pragma unroll
    for (int j = 0; j < 8; ++j) {
      dA[j] = __expf(dt[j] * An);
      cB[j] = dtu[j] * Bv[j];
      h = fmaf(h, dA[j], cB[j]);
      P *= dA[j];
    }
    float hs = h, Ps = P;
    #pragma unroll
    for (int off = 1; off < 64; off <<= 1) {
      const float hp = __shfl_up(hs, off, 64);
      const float Pp = __shfl_up(Ps, off, 64);
      if (lane >= off) { hs = fmaf(hp, Ps, hs); Ps *= Pp; }
    }
    float h0 = __shfl_up(hs, 1, 64);
    if (lane == 0) h0 = 0.f;
    #pragma unroll
    for (int j = 0; j < 8; ++j) {
      h0 = fmaf(h0, dA[j], cB[j]);
      out[j] = fmaf(h0, Cv[j], out[j]);
    }
  }
  #pragma unroll
  for (int j = 0; j < 8; ++j) out[j] = fmaf(Dv, u[j], out[j]);
}

__global__ __launch_bounds__(512) void scan_split_kernel(
    const float* __restrict__ delta_f, const float* __restrict__ delta_r,
    const float* __restrict__ xbc_f, const float* __restrict__ xbc_r,
    const float* __restrict__ Alog_f, const float* __restrict__ Alog_r,
    const float* __restrict__ Dsk_f, const float* __restrict__ Dsk_r,
    const float* __restrict__ cw_f, const float* __restrict__ cb_f,
    const float* __restrict__ cw_r, const float* __restrict__ cb_r,
    const float* __restrict__ xz, unsigned short* __restrict__ ybt) {
  __shared__ float s_r[4][512];
  __shared__ unsigned short s_y[4][512];
  const int t = threadIdx.x;           // 0..511
  const int wv = t >> 6;               // 0..7
  const int lane = t & 63;
  const int dir = wv & 1;
  const int dl = wv >> 1;              // local d 0..3
  const int row = blockIdx.x * 4 + dl;
  const int b = row >> 10, d = row & 1023;
  const long rbase = (long)d * NBL + b * SEQ;

  // ---- load x row ----
  float xv[8];
  {
    const float* xp = xz + rbase + lane * 8;
    const float4 a0 = *(const float4*)&xp[0];
    const float4 a1 = *(const float4*)&xp[4];
    xv[0] = a0.x; xv[1] = a0.y; xv[2] = a0.z; xv[3] = a0.w;
    xv[4] = a1.x; xv[5] = a1.y; xv[6] = a1.z; xv[7] = a1.w;
  }
  // reverse waves work on mirrored x
  if (dir) {
    float xr[8];
    #pragma unroll
    for (int j = 0; j < 8; ++j) xr[j] = __shfl(xv[7 - j], 63 - lane, 64);
    #pragma unroll
    for (int j = 0; j < 8; ++j) xv[j] = xr[j];
  }
  // ---- conv + silu (this dir) ----
  const float* cwp = dir ? cw_r : cw_f;
  const float* cbp = dir ? cb_r : cb_f;
  float u[8];
  {
    const float cw0 = cwp[d * 4], cw1 = cwp[d * 4 + 1], cw2 = cwp[d * 4 + 2],
                cw3 = cwp[d * 4 + 3], cb = cbp[d];
    const float xm1 = __shfl_up(xv[7], 1, 64);
    const float xm2 = __shfl_up(xv[6], 1, 64);
    const float xm3 = __shfl_up(xv[5], 1, 64);
    const float ext[3] = {xm3, xm2, xm1};
    #pragma unroll
    for (int j = 0; j < 8; ++j) {
      float s = cb + cw3 * xv[j];
      const int p = lane * 8 + j;
      #pragma unroll
      for (int k = 0; k < 3; ++k) {
        const int idx = j - 3 + k;
        const float xval = (idx >= 0) ? xv[idx] : ext[3 + idx];
        if (p - 3 + k >= 0) s += (k == 0 ? cw0 : (k == 1 ? cw1 : cw2)) * xval;
      }
      u[j] = s * sigmoidf_(s);
    }
  }

  float a[8];
  scan_pass((dir ? delta_r : delta_f) + rbase + lane * 8, u,
            (dir ? xbc_r : xbc_f) + b * SEQ + lane * 8,
            (dir ? Alog_r : Alog_f) + d * DSTATE,
            (dir ? Dsk_r : Dsk_f)[d], lane, a);

  if (dir) {
    // mirror into forward order and park
    #pragma unroll
    for (int j = 0; j < 8; ++j) {
      const float v = __shfl(a[7 - j], 63 - lane, 64);
      s_r[dl][lane * 8 + j] = v;
    }
  }
  __syncthreads();
  if (!dir) {
    const float* zp = xz + (long)(DINNER + d) * NBL + b * SEQ + lane * 8;
    const float4 z0 = *(const float4*)&zp[0];
    const float4 z1 = *(const float4*)&zp[4];
    const float zv[8] = {z0.x, z0.y, z0.z, z0.w, z1.x, z1.y, z1.z, z1.w};
    #pragma unroll
    for (int j = 0; j < 8; ++j) {
      const float tot = a[j] + s_r[dl][lane * 8 + j];
      s_y[dl][lane * 8 + j] = f2bf(tot * (zv[j] * sigmoidf_(zv[j])));
    }
  }
  __syncthreads();
  // ---- block gathers ushort4 into ybt (n, e) ----
  const int d0 = (blockIdx.x * 4) & 1023;
  const int bb = (blockIdx.x * 4) >> 10;
  unsigned short* yrow = ybt + (long)(bb * SEQ) * DINNER + d0;
  {
    const int n = t;  // 0..511
    ushort4 v = {s_y[0][n], s_y[1][n], s_y[2][n], s_y[3][n]};
    *(ushort4*)&yrow[(long)n * DINNER] = v;
  }
}

// ---------------- out_proj GEMM: 128x128, BK=64, reg-prefetch ---------------
__global__ __launch_bounds__(256) void gemm_out_kernel(
    const unsigned short* __restrict__ A, const unsigned short* __restrict__ B,
    float* __restrict__ C) {
  __shared__ unsigned short As[128 * LDK2];
  __shared__ unsigned short Bs[128 * LDK2];
  const int t = threadIdx.x;
  const int m0 = blockIdx.y * 128, n0 = blockIdx.x * 128;
  const int lane = t & 63;
  const int w = t >> 6;
  const int wr = (w >> 1) * 64, wc = (w & 1) * 64;
  const int fr = lane & 15;
  const int fq = lane >> 4;
  const int K = DINNER;

  f32x4 acc[4][4];
  #pragma unroll
  for (int i = 0; i < 4; ++i)
    #pragma unroll
    for (int j = 0; j < 4; ++j) {
      f32x4 z = {0.f, 0.f, 0.f, 0.f};
      acc[i][j] = z;
    }

  const int srow = t >> 1, sko = (t & 1) * 32;

  bf16x8 pa[4], pb[4];
  #define LOADG_OUT(k0_) do {                                              \
    const unsigned short* ap = &A[(long)(m0 + srow) * K + (k0_) + sko];    \
    pa[0] = *(const bf16x8*)ap;        pa[1] = *(const bf16x8*)(ap + 8);   \
    pa[2] = *(const bf16x8*)(ap + 16); pa[3] = *(const bf16x8*)(ap + 24);  \
    const unsigned short* bp = &B[(long)(n0 + srow) * K + (k0_) + sko];    \
    pb[0] = *(const bf16x8*)bp;        pb[1] = *(const bf16x8*)(bp + 8);   \
    pb[2] = *(const bf16x8*)(bp + 16); pb[3] = *(const bf16x8*)(bp + 24);  \
  } while (0)

  LOADG_OUT(0);
  for (int k0 = 0; k0 < K; k0 += 64) {
    if (k0) __syncthreads();
    *(bf16x8*)&As[srow * LDK2 + sko]      = pa[0];
    *(bf16x8*)&As[srow * LDK2 + sko + 8]  = pa[1];
    *(bf16x8*)&As[srow * LDK2 + sko + 16] = pa[2];
    *(bf16x8*)&As[srow * LDK2 + sko + 24] = pa[3];
    *(bf16x8*)&Bs[srow * LDK2 + sko]      = pb[0];
    *(bf16x8*)&Bs[srow * LDK2 + sko + 8]  = pb[1];
    *(bf16x8*)&Bs[srow * LDK2 + sko + 16] = pb[2];
    *(bf16x8*)&Bs[srow * LDK2 + sko + 24] = pb[3];
    __syncthreads();
    if (k0 + 64 < K) LOADG_OUT(k0 + 64);
    #pragma unroll
    for (int h = 0; h < 2; ++h) {
      bf16x8 af[4], bg[4];
      #pragma unroll
      for (int i = 0; i < 4; ++i) {
        af[i] = *(const bf16x8*)&As[(wr + i * 16 + fr) * LDK2 + h * 32 + fq * 8];
        bg[i] = *(const bf16x8*)&Bs[(wc + i * 16 + fr) * LDK2 + h * 32 + fq * 8];
      }
      #pragma unroll
      for (int i = 0; i < 4; ++i)
        #pragma unroll
        for (int j = 0; j < 4; ++j)
          acc[i][j] = __builtin_amdgcn_mfma_f32_16x16x32_bf16(
              af[i], bg[j], acc[i][j], 0, 0, 0);
    }
  }
  #undef LOADG_OUT

  #pragma unroll
  for (int i = 0; i < 4; ++i)
    #pragma unroll
    for (int j = 0; j < 4; ++j)
      #pragma unroll
      for (int r2 = 0; r2 < 4; ++r2) {
        const int m = m0 + wr + i * 16 + fq * 4 + r2;
        const int n = n0 + wc + j * 16 + fr;
        C[(long)n * DMODEL + m] = acc[i][j][r2];
      }
}

extern "C" void kernel_launch(void* const* d_in, const int* in_sizes, int n_in,
                              void* d_out, int out_size, void* d_ws, size_t ws_size,
                              hipStream_t stream) {
  (void)in_sizes; (void)n_in; (void)out_size; (void)ws_size;
  const float* x       = (const float*)d_in[0];
  const float* norm_w  = (const float*)d_in[1];
  const float* in_proj = (const float*)d_in[2];
  const float* convw_f = (const float*)d_in[3];
  const float* convb_f = (const float*)d_in[4];
  const float* xpw_f   = (const float*)d_in[5];
  const float* dtw_f   = (const float*)d_in[6];
  const float* dtb_f   = (const float*)d_in[7];
  const float* Alog_f  = (const float*)d_in[8];
  const float* Dsk_f   = (const float*)d_in[9];
  const float* convw_r = (const float*)d_in[10];
  const float* convb_r = (const float*)d_in[11];
  const float* xpw_r   = (const float*)d_in[12];
  const float* dtw_r   = (const float*)d_in[13];
  const float* dtb_r   = (const float*)d_in[14];
  const float* Alog_r  = (const float*)d_in[15];
  const float* Dsk_r   = (const float*)d_in[16];
  const float* out_w   = (const float*)d_in[17];
  const float* normf_w = (const float*)d_in[18];

  float* ws = (float*)d_ws;
  float* residual = ws;  ws += 524288;
  float* xzbuf    = ws;  ws += 2097152;
  float* xbc_f    = ws;  ws += 32768;
  float* xbc_r    = ws;  ws += 32768;
  float* delta_f  = ws;  ws += 1048576;
  float* delta_r  = ws;  ws += 1048576;
  float* hnb_f    = ws;  ws += 262144;   // 1024x512 bf16
  float* wbfin_f  = ws;  ws += 2097152;  // 4x2048x512 bf16
  float* wbfout_f = ws;  ws += 1048576;  // 4x512x1024 bf16
  float* ybt_f    = ws;  ws += 524288;   // 1024x1024 bf16
  float* xcT_f    = ws;  ws += 1048576;  // 2 x 1024 x 1024 bf16
  float* dtT_f    = ws;  ws += 32768;    // 2 x 1024 x 32 bf16
  float* xpwb_f_  = ws;  ws += 131072;
  float* xpwb_r_  = ws;  ws += 131072;
  float* dtwb_f_  = ws;  ws += 65536;
  float* dtwb_r_  = ws;  ws += 65536;

  unsigned short* hnb = (unsigned short*)hnb_f;
  unsigned short* wbfin = (unsigned short*)wbfin_f;
  unsigned short* wbfout = (unsigned short*)wbfout_f;
  unsigned short* ybt = (unsigned short*)ybt_f;
  unsigned short* xcT = (unsigned short*)xcT_f;
  unsigned short* dtT = (unsigned short*)dtT_f;
  unsigned short* xpwb_f = (unsigned short*)xpwb_f_;
  unsigned short* xpwb_r = (unsigned short*)xpwb_r_;
  unsigned short* dtwb_f = (unsigned short*)dtwb_f_;
  unsigned short* dtwb_r = (unsigned short*)dtwb_r_;

  float* outp = (float*)d_out;

  wconvert_kernel<<<3456, 256, 0, stream>>>(
      in_proj, out_w, xpw_f, xpw_r, dtw_f, dtw_r,
      wbfin, wbfout, xpwb_f, xpwb_r, dtwb_f, dtwb_r);

  for (int layer = 0; layer < 4; ++layer) {
    const float* hsrc = layer == 0 ? x : (outp + (long)layer * 524288);
    addnorm_kernel<<<1024, 256, 0, stream>>>(
        hsrc, residual, norm_w + layer * DMODEL, nullptr, hnb, layer == 0 ? 1 : 0);
    gemm_in_kernel<<<dim3(16, 16), 256, 0, stream>>>(
        wbfin + (long)layer * 2048 * 512, hnb, xzbuf);
    conv_silu_kernel<<<dim3(32, 32, 2), 256, 0, stream>>>(
        xzbuf, convw_f + layer * DINNER * 4, convb_f + layer * DINNER,
        convw_r + layer * DINNER * 4, convb_r + layer * DINNER, xcT);
    xdbl_mfma_kernel<<<dim3(8, 2), 256, 0, stream>>>(
        xpwb_f + (long)layer * 64 * DINNER, xpwb_r + (long)layer * 64 * DINNER,
        xcT, dtT, xbc_f, xbc_r);
    deltam_kernel<<<dim3(8, 8, 2), 256, 0, stream>>>(
        dtwb_f + (long)layer * DINNER * DTRANK, dtwb_r + (long)layer * DINNER * DTRANK,
        dtT, dtb_f + layer * DINNER, dtb_r + layer * DINNER, delta_f, delta_r);
    scan_split_kernel<<<512, 512, 0, stream>>>(
        delta_f, delta_r, xbc_f, xbc_r,
        Alog_f + layer * DINNER * DSTATE, Alog_r + layer * DINNER * DSTATE,
        Dsk_f + layer * DINNER, Dsk_r + layer * DINNER,
        convw_f + layer * DINNER * 4, convb_f + layer * DINNER,
        convw_r + layer * DINNER * 4, convb_r + layer * DINNER,
        xzbuf, ybt);
    gemm_out_kernel<<<dim3(8, 4), 256, 0, stream>>>(
        wbfout + (long)layer * 512 * 1024, ybt,
        outp + (long)(1 + layer) * 524288);
  }
  addnorm_kernel<<<1024, 256, 0, stream>>>(
      outp + 4 * 524288, residual, normf_w, outp, nullptr, 0);
}

// Round 15
// 328.348 us; speedup vs baseline: 1.4019x; 1.1168x over previous
//
#include <hip/hip_runtime.h>

#define BATCH 2
#define SEQ 512
#define DMODEL 512
#define DINNER 1024
#define DSTATE 16
#define DTRANK 32
#define NBL (BATCH*SEQ)      // 1024
#define EPSV 1e-5f

typedef __attribute__((ext_vector_type(8))) short bf16x8;
typedef __attribute__((ext_vector_type(4))) float f32x4;

static __device__ __forceinline__ float sigmoidf_(float x) {
  return 1.0f / (1.0f + __expf(-x));
}
static __device__ __forceinline__ float softplusf_(float x) {
  return fmaxf(x, 0.0f) + log1pf(__expf(-fabsf(x)));
}
static __device__ __forceinline__ unsigned short f2bf(float x) {
  unsigned int u = __float_as_uint(x);
  unsigned int r = (u + 0x7FFFu + ((u >> 16) & 1u)) >> 16;
  return (unsigned short)r;
}

// ---------------- all-weight fp32 -> bf16 convert (segmented) ----------------
__global__ __launch_bounds__(256) void wconvert_kernel(
    const float* __restrict__ s0, const float* __restrict__ s1,
    const float* __restrict__ s2, const float* __restrict__ s3,
    const float* __restrict__ s4, const float* __restrict__ s5,
    unsigned short* __restrict__ d0, unsigned short* __restrict__ d1,
    unsigned short* __restrict__ d2, unsigned short* __restrict__ d3,
    unsigned short* __restrict__ d4, unsigned short* __restrict__ d5) {
  long i = (long)(blockIdx.x * 256 + threadIdx.x) * 8;
  const float* src; unsigned short* dst;
  if (i < 4194304)      { src = s0; dst = d0; }
  else if (i < 6291456) { src = s1; dst = d1; i -= 4194304; }
  else if (i < 6553600) { src = s2; dst = d2; i -= 6291456; }
  else if (i < 6815744) { src = s3; dst = d3; i -= 6553600; }
  else if (i < 6946816) { src = s4; dst = d4; i -= 6815744; }
  else                  { src = s5; dst = d5; i -= 6946816; }
  const float4 v0 = *(const float4*)&src[i];
  const float4 v1 = *(const float4*)&src[i + 4];
  bf16x8 o;
  o[0] = (short)f2bf(v0.x); o[1] = (short)f2bf(v0.y);
  o[2] = (short)f2bf(v0.z); o[3] = (short)f2bf(v0.w);
  o[4] = (short)f2bf(v1.x); o[5] = (short)f2bf(v1.y);
  o[6] = (short)f2bf(v1.z); o[7] = (short)f2bf(v1.w);
  *(bf16x8*)&dst[i] = o;
}

// ---------------- fused add + RMSNorm ----------------
__global__ __launch_bounds__(256) void addnorm_kernel(
    const float* __restrict__ hs, float* __restrict__ residual,
    const float* __restrict__ w, float* __restrict__ out,
    unsigned short* __restrict__ outb, int first) {
  const int row = blockIdx.x;
  const int t = threadIdx.x;
  const float* hp = hs + (long)row * DMODEL;
  float* rp = residual + (long)row * DMODEL;
  float r0 = hp[t], r1 = hp[t + 256];
  if (!first) { r0 += rp[t]; r1 += rp[t + 256]; }
  rp[t] = r0; rp[t + 256] = r1;
  float ss = r0 * r0 + r1 * r1;
  #pragma unroll
  for (int off = 32; off; off >>= 1) ss += __shfl_xor(ss, off, 64);
  __shared__ float sw[4];
  const int wid = t >> 6, lane = t & 63;
  if (lane == 0) sw[wid] = ss;
  __syncthreads();
  const float tot = sw[0] + sw[1] + sw[2] + sw[3];
  const float scale = rsqrtf(tot * (1.0f / (float)DMODEL) + EPSV);
  const float v0 = r0 * scale * w[t];
  const float v1 = r1 * scale * w[t + 256];
  if (out) {
    out[(long)row * DMODEL + t] = v0;
    out[(long)row * DMODEL + t + 256] = v1;
  }
  if (outb) {
    outb[(long)row * DMODEL + t] = f2bf(v0);
    outb[(long)row * DMODEL + t + 256] = f2bf(v1);
  }
}

#define LDK 40
#define LDK2 72

// ---------------- in_proj GEMM: 128M x 64N, BK=64, reg-prefetch -------------
__global__ __launch_bounds__(256) void gemm_in_kernel(
    const unsigned short* __restrict__ A, const unsigned short* __restrict__ B,
    float* __restrict__ C) {
  __shared__ unsigned short As[128 * LDK2];
  __shared__ unsigned short Bs[64 * LDK2];
  const int t = threadIdx.x;
  const int m0 = blockIdx.y * 128, n0 = blockIdx.x * 64;
  const int lane = t & 63;
  const int w = t >> 6;
  const int wr = (w >> 1) * 64, wc = (w & 1) * 32;
  const int fr = lane & 15;
  const int fq = lane >> 4;
  const int K = DMODEL;

  f32x4 acc[4][2];
  #pragma unroll
  for (int i = 0; i < 4; ++i)
    #pragma unroll
    for (int j = 0; j < 2; ++j) {
      f32x4 z = {0.f, 0.f, 0.f, 0.f};
      acc[i][j] = z;
    }

  const int arow = t >> 1, ako = (t & 1) * 32;   // A: 128 x 64
  const int brow = t >> 2, bko = (t & 3) * 16;   // B: 64 x 64

  bf16x8 pa[4], pb[2];
  #define LOADG_IN(k0_) do {                                              \
    const unsigned short* ap = &A[(long)(m0 + arow) * K + (k0_) + ako];   \
    pa[0] = *(const bf16x8*)ap;        pa[1] = *(const bf16x8*)(ap + 8);  \
    pa[2] = *(const bf16x8*)(ap + 16); pa[3] = *(const bf16x8*)(ap + 24); \
    const unsigned short* bp = &B[(long)(n0 + brow) * K + (k0_) + bko];   \
    pb[0] = *(const bf16x8*)bp;        pb[1] = *(const bf16x8*)(bp + 8);  \
  } while (0)

  LOADG_IN(0);
  for (int k0 = 0; k0 < K; k0 += 64) {
    if (k0) __syncthreads();
    *(bf16x8*)&As[arow * LDK2 + ako]      = pa[0];
    *(bf16x8*)&As[arow * LDK2 + ako + 8]  = pa[1];
    *(bf16x8*)&As[arow * LDK2 + ako + 16] = pa[2];
    *(bf16x8*)&As[arow * LDK2 + ako + 24] = pa[3];
    *(bf16x8*)&Bs[brow * LDK2 + bko]      = pb[0];
    *(bf16x8*)&Bs[brow * LDK2 + bko + 8]  = pb[1];
    __syncthreads();
    if (k0 + 64 < K) LOADG_IN(k0 + 64);
    #pragma unroll
    for (int h = 0; h < 2; ++h) {
      bf16x8 af[4], bg[2];
      #pragma unroll
      for (int i = 0; i < 4; ++i)
        af[i] = *(const bf16x8*)&As[(wr + i * 16 + fr) * LDK2 + h * 32 + fq * 8];
      #pragma unroll
      for (int j = 0; j < 2; ++j)
        bg[j] = *(const bf16x8*)&Bs[(wc + j * 16 + fr) * LDK2 + h * 32 + fq * 8];
      #pragma unroll
      for (int i = 0; i < 4; ++i)
        #pragma unroll
        for (int j = 0; j < 2; ++j)
          acc[i][j] = __builtin_amdgcn_mfma_f32_16x16x32_bf16(
              af[i], bg[j], acc[i][j], 0, 0, 0);
    }
  }
  #undef LOADG_IN

  #pragma unroll
  for (int i = 0; i < 4; ++i)
    #pragma unroll
    for (int j = 0; j < 2; ++j)
      #pragma unroll
      for (int r2 = 0; r2 < 4; ++r2) {
        const int m = m0 + wr + i * 16 + fq * 4 + r2;
        const int n = n0 + wc + j * 16 + fr;
        C[(long)m * NBL + n] = acc[i][j][r2];
      }
}

// ---------------- conv+SiLU -> transposed bf16 xcT only ----------------
__global__ __launch_bounds__(256) void conv_silu_kernel(
    const float* __restrict__ xz,
    const float* __restrict__ cw_f, const float* __restrict__ cb_f,
    const float* __restrict__ cw_r, const float* __restrict__ cb_r,
    unsigned short* __restrict__ xcT) {
  __shared__ unsigned short tile[32][33];
  const int dir = blockIdx.z;
  const int n0 = blockIdx.x * 32, d0 = blockIdx.y * 32;
  const int b = n0 >> 9;
  const int l0 = n0 & (SEQ - 1);
  const float* cw = dir ? cw_r : cw_f;
  const float* cb = dir ? cb_r : cb_f;
  unsigned short* dst = xcT + (long)dir * DINNER * NBL;
  const int t = threadIdx.x;
  const int c = t & 31, rr = t >> 5;
  #pragma unroll
  for (int p = 0; p < 4; ++p) {
    const int d = d0 + p * 8 + rr;
    const int l = l0 + c;
    const float* xi = xz + (long)d * NBL + b * SEQ;
    float sum = cb[d];
    #pragma unroll
    for (int k = 0; k < 4; ++k) {
      const int tt = l - 3 + k;
      if (tt >= 0) {
        const int src = dir ? (SEQ - 1 - tt) : tt;
        sum += cw[d * 4 + k] * xi[src];
      }
    }
    const float v = sum * sigmoidf_(sum);
    tile[p * 8 + rr][c] = f2bf(v);
  }
  __syncthreads();
  #pragma unroll
  for (int p = 0; p < 4; ++p) {
    const int n = n0 + p * 8 + rr;
    dst[(long)n * DINNER + d0 + c] = tile[c][p * 8 + rr];
  }
}

// ---------------- x_dbl via MFMA: 64M x 32N, BK=64, grid (32,2) -------------
// rows<32 -> dtT bf16 (dir,n,32); rows>=32 -> xbcT fp32 [slot][NBL].
__global__ __launch_bounds__(256) void xdbl_mfma_kernel(
    const unsigned short* __restrict__ xpwb_f, const unsigned short* __restrict__ xpwb_r,
    const unsigned short* __restrict__ xcT,
    unsigned short* __restrict__ dtT,
    float* __restrict__ xbc_f, float* __restrict__ xbc_r) {
  __shared__ unsigned short As[64 * LDK2];
  __shared__ unsigned short Bs[32 * LDK2];
  const int t = threadIdx.x;
  const int dir = blockIdx.y;
  const int n0 = blockIdx.x * 32;
  const unsigned short* A = dir ? xpwb_r : xpwb_f;
  const unsigned short* B = xcT + (long)dir * DINNER * NBL;
  float* xbc = dir ? xbc_r : xbc_f;
  unsigned short* dtt = dtT + (long)dir * NBL * DTRANK;

  const int lane = t & 63;
  const int w = t >> 6;
  const int wr = (w >> 1) * 32, wc = (w & 1) * 16;
  const int fr = lane & 15;
  const int fq = lane >> 4;

  f32x4 acc[2];
  #pragma unroll
  for (int i = 0; i < 2; ++i) {
    f32x4 z = {0.f, 0.f, 0.f, 0.f};
    acc[i] = z;
  }

  const int arow = t >> 2, ako = (t & 3) * 16;   // A: 64 x 64
  const int brow = t >> 3, bko = (t & 7) * 8;    // B: 32 x 64

  bf16x8 pa[2], pb;
  #define LOADG_XD(k0_) do {                                                   \
    const unsigned short* ap = &A[(long)arow * DINNER + (k0_) + ako];          \
    pa[0] = *(const bf16x8*)ap;        pa[1] = *(const bf16x8*)(ap + 8);       \
    pb = *(const bf16x8*)&B[(long)(n0 + brow) * DINNER + (k0_) + bko];         \
  } while (0)

  LOADG_XD(0);
  for (int k0 = 0; k0 < DINNER; k0 += 64) {
    if (k0) __syncthreads();
    *(bf16x8*)&As[arow * LDK2 + ako]     = pa[0];
    *(bf16x8*)&As[arow * LDK2 + ako + 8] = pa[1];
    *(bf16x8*)&Bs[brow * LDK2 + bko]     = pb;
    __syncthreads();
    if (k0 + 64 < DINNER) LOADG_XD(k0 + 64);
    #pragma unroll
    for (int h = 0; h < 2; ++h) {
      bf16x8 af[2], bg;
      #pragma unroll
      for (int i = 0; i < 2; ++i)
        af[i] = *(const bf16x8*)&As[(wr + i * 16 + fr) * LDK2 + h * 32 + fq * 8];
      bg = *(const bf16x8*)&Bs[(wc + fr) * LDK2 + h * 32 + fq * 8];
      #pragma unroll
      for (int i = 0; i < 2; ++i)
        acc[i] = __builtin_amdgcn_mfma_f32_16x16x32_bf16(af[i], bg, acc[i], 0, 0, 0);
    }
  }
  #undef LOADG_XD

  #pragma unroll
  for (int i = 0; i < 2; ++i)
    #pragma unroll
    for (int r2 = 0; r2 < 4; ++r2) {
      const int m = wr + i * 16 + fq * 4 + r2;
      const int n = n0 + wc + fr;
      const float v = acc[i][r2];
      if (m < DTRANK) dtt[(long)n * DTRANK + m] = f2bf(v);
      else xbc[(long)(m - 32) * NBL + n] = v;   // slot-major
    }
}

// ---------------- delta via MFMA: softplus(dtw @ dt + dtb) ----------------
__global__ __launch_bounds__(256) void deltam_kernel(
    const unsigned short* __restrict__ dtwb_f, const unsigned short* __restrict__ dtwb_r,
    const unsigned short* __restrict__ dtT,
    const float* __restrict__ dtb_f, const float* __restrict__ dtb_r,
    float* __restrict__ delta_f, float* __restrict__ delta_r) {
  __shared__ unsigned short As[128 * LDK];
  __shared__ unsigned short Bs[128 * LDK];
  const int t = threadIdx.x;
  const int dir = blockIdx.z;
  const unsigned short* A = dir ? dtwb_r : dtwb_f;
  const unsigned short* B = dtT + (long)dir * NBL * DTRANK;
  const float* dtb = dir ? dtb_r : dtb_f;
  float* dl = dir ? delta_r : delta_f;
  const int m0 = blockIdx.y * 128, n0 = blockIdx.x * 128;
  const int lane = t & 63;
  const int w = t >> 6;
  const int wr = (w >> 1) * 64, wc = (w & 1) * 64;
  const int fr = lane & 15;
  const int fq = lane >> 4;

  const int srow = t >> 1;
  const int sko = (t & 1) * 16;
  *(bf16x8*)&As[srow * LDK + sko] =
      *(const bf16x8*)&A[(long)(m0 + srow) * DTRANK + sko];
  *(bf16x8*)&As[srow * LDK + sko + 8] =
      *(const bf16x8*)&A[(long)(m0 + srow) * DTRANK + sko + 8];
  *(bf16x8*)&Bs[srow * LDK + sko] =
      *(const bf16x8*)&B[(long)(n0 + srow) * DTRANK + sko];
  *(bf16x8*)&Bs[srow * LDK + sko + 8] =
      *(const bf16x8*)&B[(long)(n0 + srow) * DTRANK + sko + 8];
  __syncthreads();

  bf16x8 af[4], bg[4];
  #pragma unroll
  for (int i = 0; i < 4; ++i) {
    af[i] = *(const bf16x8*)&As[(wr + i * 16 + fr) * LDK + fq * 8];
    bg[i] = *(const bf16x8*)&Bs[(wc + i * 16 + fr) * LDK + fq * 8];
  }
  f32x4 acc[4][4];
  #pragma unroll
  for (int i = 0; i < 4; ++i)
    #pragma unroll
    for (int j = 0; j < 4; ++j) {
      f32x4 z = {0.f, 0.f, 0.f, 0.f};
      acc[i][j] = __builtin_amdgcn_mfma_f32_16x16x32_bf16(af[i], bg[j], z, 0, 0, 0);
    }

  #pragma unroll
  for (int i = 0; i < 4; ++i) {
    const int m = m0 + wr + i * 16 + fq * 4;
    #pragma unroll
    for (int r2 = 0; r2 < 4; ++r2) {
      const float bias = dtb[m + r2];
      #pragma unroll
      for (int j = 0; j < 4; ++j) {
        const int n = n0 + wc + j * 16 + fr;
        dl[(long)(m + r2) * NBL + n] = softplusf_(acc[i][j][r2] + bias);
      }
    }
  }
}

// ---------------- fused conv+scan+gate+transpose, dir-split waves -----------
static __device__ __forceinline__ void scan_pass(
    const float* __restrict__ dp, const float u[8],
    const float* __restrict__ bct, const float* __restrict__ Alog,
    float Dv, int lane, float out[8]) {
  float dt[8], dtu[8];
  {
    const float4 a0 = *(const float4*)&dp[0];
    const float4 a1 = *(const float4*)&dp[4];
    dt[0] = a0.x; dt[1] = a0.y; dt[2] = a0.z; dt[3] = a0.w;
    dt[4] = a1.x; dt[5] = a1.y; dt[6] = a1.z; dt[7] = a1.w;
  }
  #pragma unroll
  for (int j = 0; j < 8; ++j) { dtu[j] = dt[j] * u[j]; out[j] = 0.f; }

  for (int n = 0; n < DSTATE; ++n) {
    const float An = -__expf(Alog[n]);
    float Bv[8], Cv[8], dA[8], cB[8];
    {
      const float* bp = bct + (long)n * NBL;
      const float* cp = bct + (long)(DSTATE + n) * NBL;
      const float4 b0 = *(const float4*)&bp[0];
      const float4 b1 = *(const float4*)&bp[4];
      Bv[0] = b0.x; Bv[1] = b0.y; Bv[2] = b0.z; Bv[3] = b0.w;
      Bv[4] = b1.x; Bv[5] = b1.y; Bv[6] = b1.z; Bv[7] = b1.w;
      const float4 c0 = *(const float4*)&cp[0];
      const float4 c1 = *(const float4*)&cp[4];
      Cv[0] = c0.x; Cv[1] = c0.y; Cv[2] = c0.z; Cv[3] = c0.w;
      Cv[4] = c1.x; Cv[5] = c1.y; Cv[6] = c1.z; Cv[7] = c1.w;
    }
    float h = 0.f, P = 1.f;
    #pragma unroll
    for (int j = 0; j < 8; ++j) {
      dA[j] = __expf(dt[j] * An);
      cB[j] = dtu[j] * Bv[j];
      h = fmaf(h, dA[j], cB[j]);
      P *= dA[j];
    }
    float hs = h, Ps = P;
    #pragma unroll
    for (int off = 1; off < 64; off <<= 1) {
      const float hp = __shfl_up(hs, off, 64);
      const float Pp = __shfl_up(Ps, off, 64);
      if (lane >= off) { hs = fmaf(hp, Ps, hs); Ps *= Pp; }
    }
    float h0 = __shfl_up(hs, 1, 64);
    if (lane == 0) h0 = 0.f;
    #pragma unroll
    for (int j = 0; j < 8; ++j) {
      h0 = fmaf(h0, dA[j], cB[j]);
      out[j] = fmaf(h0, Cv[j], out[j]);
    }
  }
  #pragma unroll
  for (int j = 0; j < 8; ++j) out[j] = fmaf(Dv, u[j], out[j]);
}

__global__ __launch_bounds__(512) void scan_split_kernel(
    const float* __restrict__ delta_f, const float* __restrict__ delta_r,
    const float* __restrict__ xbc_f, const float* __restrict__ xbc_r,
    const float* __restrict__ Alog_f, const float* __restrict__ Alog_r,
    const float* __restrict__ Dsk_f, const float* __restrict__ Dsk_r,
    const float* __restrict__ cw_f, const float* __restrict__ cb_f,
    const float* __restrict__ cw_r, const float* __restrict__ cb_r,
    const float* __restrict__ xz, unsigned short* __restrict__ ybt) {
  __shared__ float s_r[4][512];
  __shared__ unsigned short s_y[4][512];
  const int t = threadIdx.x;           // 0..511
  const int wv = t >> 6;               // 0..7
  const int lane = t & 63;
  const int dir = wv & 1;
  const int dl = wv >> 1;              // local d 0..3
  const int row = blockIdx.x * 4 + dl;
  const int b = row >> 10, d = row & 1023;
  const long rbase = (long)d * NBL + b * SEQ;

  float xv[8];
  {
    const float* xp = xz + rbase + lane * 8;
    const float4 a0 = *(const float4*)&xp[0];
    const float4 a1 = *(const float4*)&xp[4];
    xv[0] = a0.x; xv[1] = a0.y; xv[2] = a0.z; xv[3] = a0.w;
    xv[4] = a1.x; xv[5] = a1.y; xv[6] = a1.z; xv[7] = a1.w;
  }
  if (dir) {
    float xr[8];
    #pragma unroll
    for (int j = 0; j < 8; ++j) xr[j] = __shfl(xv[7 - j], 63 - lane, 64);
    #pragma unroll
    for (int j = 0; j < 8; ++j) xv[j] = xr[j];
  }
  const float* cwp = dir ? cw_r : cw_f;
  const float* cbp = dir ? cb_r : cb_f;
  float u[8];
  {
    const float cw0 = cwp[d * 4], cw1 = cwp[d * 4 + 1], cw2 = cwp[d * 4 + 2],
                cw3 = cwp[d * 4 + 3], cb = cbp[d];
    const float xm1 = __shfl_up(xv[7], 1, 64);
    const float xm2 = __shfl_up(xv[6], 1, 64);
    const float xm3 = __shfl_up(xv[5], 1, 64);
    const float ext[3] = {xm3, xm2, xm1};
    #pragma unroll
    for (int j = 0; j < 8; ++j) {
      float s = cb + cw3 * xv[j];
      const int p = lane * 8 + j;
      #pragma unroll
      for (int k = 0; k < 3; ++k) {
        const int idx = j - 3 + k;
        const float xval = (idx >= 0) ? xv[idx] : ext[3 + idx];
        if (p - 3 + k >= 0) s += (k == 0 ? cw0 : (k == 1 ? cw1 : cw2)) * xval;
      }
      u[j] = s * sigmoidf_(s);
    }
  }

  float a[8];
  scan_pass((dir ? delta_r : delta_f) + rbase + lane * 8, u,
            (dir ? xbc_r : xbc_f) + b * SEQ + lane * 8,
            (dir ? Alog_r : Alog_f) + d * DSTATE,
            (dir ? Dsk_r : Dsk_f)[d], lane, a);

  if (dir) {
    #pragma unroll
    for (int j = 0; j < 8; ++j) {
      const float v = __shfl(a[7 - j], 63 - lane, 64);
      s_r[dl][lane * 8 + j] = v;
    }
  }
  __syncthreads();
  if (!dir) {
    const float* zp = xz + (long)(DINNER + d) * NBL + b * SEQ + lane * 8;
    const float4 z0 = *(const float4*)&zp[0];
    const float4 z1 = *(const float4*)&zp[4];
    const float zv[8] = {z0.x, z0.y, z0.z, z0.w, z1.x, z1.y, z1.z, z1.w};
    #pragma unroll
    for (int j = 0; j < 8; ++j) {
      const float tot = a[j] + s_r[dl][lane * 8 + j];
      s_y[dl][lane * 8 + j] = f2bf(tot * (zv[j] * sigmoidf_(zv[j])));
    }
  }
  __syncthreads();
  const int d0 = (blockIdx.x * 4) & 1023;
  const int bb = (blockIdx.x * 4) >> 10;
  unsigned short* yrow = ybt + (long)(bb * SEQ) * DINNER + d0;
  {
    const int n = t;  // 0..511
    ushort4 v = {s_y[0][n], s_y[1][n], s_y[2][n], s_y[3][n]};
    *(ushort4*)&yrow[(long)n * DINNER] = v;
  }
}

// ---------------- out_proj GEMM: 64x64 tile, grid (16,8), BK=64 -------------
__global__ __launch_bounds__(256) void gemm_out_kernel(
    const unsigned short* __restrict__ A, const unsigned short* __restrict__ B,
    float* __restrict__ C) {
  __shared__ unsigned short As[64 * LDK2];
  __shared__ unsigned short Bs[64 * LDK2];
  const int t = threadIdx.x;
  const int m0 = blockIdx.y * 64, n0 = blockIdx.x * 64;
  const int lane = t & 63;
  const int w = t >> 6;
  const int wr = (w >> 1) * 32, wc = (w & 1) * 32;
  const int fr = lane & 15;
  const int fq = lane >> 4;
  const int K = DINNER;

  f32x4 acc[2][2];
  #pragma unroll
  for (int i = 0; i < 2; ++i)
    #pragma unroll
    for (int j = 0; j < 2; ++j) {
      f32x4 z = {0.f, 0.f, 0.f, 0.f};
      acc[i][j] = z;
    }

  const int arow = t >> 2, ako = (t & 3) * 16;   // 64 x 64 each

  bf16x8 pa[2], pb[2];
  #define LOADG_OUT(k0_) do {                                              \
    const unsigned short* ap = &A[(long)(m0 + arow) * K + (k0_) + ako];    \
    pa[0] = *(const bf16x8*)ap;        pa[1] = *(const bf16x8*)(ap + 8);   \
    const unsigned short* bp = &B[(long)(n0 + arow) * K + (k0_) + ako];    \
    pb[0] = *(const bf16x8*)bp;        pb[1] = *(const bf16x8*)(bp + 8);   \
  } while (0)

  LOADG_OUT(0);
  for (int k0 = 0; k0 < K; k0 += 64) {
    if (k0) __syncthreads();
    *(bf16x8*)&As[arow * LDK2 + ako]     = pa[0];
    *(bf16x8*)&As[arow * LDK2 + ako + 8] = pa[1];
    *(bf16x8*)&Bs[arow * LDK2 + ako]     = pb[0];
    *(bf16x8*)&Bs[arow * LDK2 + ako + 8] = pb[1];
    __syncthreads();
    if (k0 + 64 < K) LOADG_OUT(k0 + 64);
    #pragma unroll
    for (int h = 0; h < 2; ++h) {
      bf16x8 af[2], bg[2];
      #pragma unroll
      for (int i = 0; i < 2; ++i) {
        af[i] = *(const bf16x8*)&As[(wr + i * 16 + fr) * LDK2 + h * 32 + fq * 8];
        bg[i] = *(const bf16x8*)&Bs[(wc + i * 16 + fr) * LDK2 + h * 32 + fq * 8];
      }
      #pragma unroll
      for (int i = 0; i < 2; ++i)
        #pragma unroll
        for (int j = 0; j < 2; ++j)
          acc[i][j] = __builtin_amdgcn_mfma_f32_16x16x32_bf16(
              af[i], bg[j], acc[i][j], 0, 0, 0);
    }
  }
  #undef LOADG_OUT

  #pragma unroll
  for (int i = 0; i < 2; ++i)
    #pragma unroll
    for (int j = 0; j < 2; ++j)
      #pragma unroll
      for (int r2 = 0; r2 < 4; ++r2) {
        const int m = m0 + wr + i * 16 + fq * 4 + r2;
        const int n = n0 + wc + j * 16 + fr;
        C[(long)n * DMODEL + m] = acc[i][j][r2];
      }
}

extern "C" void kernel_launch(void* const* d_in, const int* in_sizes, int n_in,
                              void* d_out, int out_size, void* d_ws, size_t ws_size,
                              hipStream_t stream) {
  (void)in_sizes; (void)n_in; (void)out_size; (void)ws_size;
  const float* x       = (const float*)d_in[0];
  const float* norm_w  = (const float*)d_in[1];
  const float* in_proj = (const float*)d_in[2];
  const float* convw_f = (const float*)d_in[3];
  const float* convb_f = (const float*)d_in[4];
  const float* xpw_f   = (const float*)d_in[5];
  const float* dtw_f   = (const float*)d_in[6];
  const float* dtb_f   = (const float*)d_in[7];
  const float* Alog_f  = (const float*)d_in[8];
  const float* Dsk_f   = (const float*)d_in[9];
  const float* convw_r = (const float*)d_in[10];
  const float* convb_r = (const float*)d_in[11];
  const float* xpw_r   = (const float*)d_in[12];
  const float* dtw_r   = (const float*)d_in[13];
  const float* dtb_r   = (const float*)d_in[14];
  const float* Alog_r  = (const float*)d_in[15];
  const float* Dsk_r   = (const float*)d_in[16];
  const float* out_w   = (const float*)d_in[17];
  const float* normf_w = (const float*)d_in[18];

  float* ws = (float*)d_ws;
  float* residual = ws;  ws += 524288;
  float* xzbuf    = ws;  ws += 2097152;
  float* xbc_f    = ws;  ws += 32768;
  float* xbc_r    = ws;  ws += 32768;
  float* delta_f  = ws;  ws += 1048576;
  float* delta_r  = ws;  ws += 1048576;
  float* hnb_f    = ws;  ws += 262144;   // 1024x512 bf16
  float* wbfin_f  = ws;  ws += 2097152;  // 4x2048x512 bf16
  float* wbfout_f = ws;  ws += 1048576;  // 4x512x1024 bf16
  float* ybt_f    = ws;  ws += 524288;   // 1024x1024 bf16
  float* xcT_f    = ws;  ws += 1048576;  // 2 x 1024 x 1024 bf16
  float* dtT_f    = ws;  ws += 32768;    // 2 x 1024 x 32 bf16
  float* xpwb_f_  = ws;  ws += 131072;
  float* xpwb_r_  = ws;  ws += 131072;
  float* dtwb_f_  = ws;  ws += 65536;
  float* dtwb_r_  = ws;  ws += 65536;

  unsigned short* hnb = (unsigned short*)hnb_f;
  unsigned short* wbfin = (unsigned short*)wbfin_f;
  unsigned short* wbfout = (unsigned short*)wbfout_f;
  unsigned short* ybt = (unsigned short*)ybt_f;
  unsigned short* xcT = (unsigned short*)xcT_f;
  unsigned short* dtT = (unsigned short*)dtT_f;
  unsigned short* xpwb_f = (unsigned short*)xpwb_f_;
  unsigned short* xpwb_r = (unsigned short*)xpwb_r_;
  unsigned short* dtwb_f = (unsigned short*)dtwb_f_;
  unsigned short* dtwb_r = (unsigned short*)dtwb_r_;

  float* outp = (float*)d_out;

  wconvert_kernel<<<3456, 256, 0, stream>>>(
      in_proj, out_w, xpw_f, xpw_r, dtw_f, dtw_r,
      wbfin, wbfout, xpwb_f, xpwb_r, dtwb_f, dtwb_r);

  for (int layer = 0; layer < 4; ++layer) {
    const float* hsrc = layer == 0 ? x : (outp + (long)layer * 524288);
    addnorm_kernel<<<1024, 256, 0, stream>>>(
        hsrc, residual, norm_w + layer * DMODEL, nullptr, hnb, layer == 0 ? 1 : 0);
    gemm_in_kernel<<<dim3(16, 16), 256, 0, stream>>>(
        wbfin + (long)layer * 2048 * 512, hnb, xzbuf);
    conv_silu_kernel<<<dim3(32, 32, 2), 256, 0, stream>>>(
        xzbuf, convw_f + layer * DINNER * 4, convb_f + layer * DINNER,
        convw_r + layer * DINNER * 4, convb_r + layer * DINNER, xcT);
    xdbl_mfma_kernel<<<dim3(32, 2), 256, 0, stream>>>(
        xpwb_f + (long)layer * 64 * DINNER, xpwb_r + (long)layer * 64 * DINNER,
        xcT, dtT, xbc_f, xbc_r);
    deltam_kernel<<<dim3(8, 8, 2), 256, 0, stream>>>(
        dtwb_f + (long)layer * DINNER * DTRANK, dtwb_r + (long)layer * DINNER * DTRANK,
        dtT, dtb_f + layer * DINNER, dtb_r + layer * DINNER, delta_f, delta_r);
    scan_split_kernel<<<512, 512, 0, stream>>>(
        delta_f, delta_r, xbc_f, xbc_r,
        Alog_f + layer * DINNER * DSTATE, Alog_r + layer * DINNER * DSTATE,
        Dsk_f + layer * DINNER, Dsk_r + layer * DINNER,
        convw_f + layer * DINNER * 4, convb_f + layer * DINNER,
        convw_r + layer * DINNER * 4, convb_r + layer * DINNER,
        xzbuf, ybt);
    gemm_out_kernel<<<dim3(16, 8), 256, 0, stream>>>(
        wbfout + (long)layer * 512 * 1024, ybt,
        outp + (long)(1 + layer) * 524288);
  }
  addnorm_kernel<<<1024, 256, 0, stream>>>(
      outp + 4 * 524288, residual, normf_w, outp, nullptr, 0);
}

// Round 16
// 315.554 us; speedup vs baseline: 1.4587x; 1.0405x over previous
//
#include <hip/hip_runtime.h>

#define BATCH 2
#define SEQ 512
#define DMODEL 512
#define DINNER 1024
#define DSTATE 16
#define DTRANK 32
#define NBL (BATCH*SEQ)      // 1024
#define EPSV 1e-5f

typedef __attribute__((ext_vector_type(8))) short bf16x8;
typedef __attribute__((ext_vector_type(4))) float f32x4;

static __device__ __forceinline__ float sigmoidf_(float x) {
  return 1.0f / (1.0f + __expf(-x));
}
static __device__ __forceinline__ float softplusf_(float x) {
  return fmaxf(x, 0.0f) + log1pf(__expf(-fabsf(x)));
}
static __device__ __forceinline__ unsigned short f2bf(float x) {
  unsigned int u = __float_as_uint(x);
  unsigned int r = (u + 0x7FFFu + ((u >> 16) & 1u)) >> 16;
  return (unsigned short)r;
}
static __device__ __forceinline__ float bf2f(short s) {
  return __uint_as_float(((unsigned int)(unsigned short)s) << 16);
}

// ---------------- all-weight fp32 -> bf16 convert (segmented) ----------------
__global__ __launch_bounds__(256) void wconvert_kernel(
    const float* __restrict__ s0, const float* __restrict__ s1,
    const float* __restrict__ s2, const float* __restrict__ s3,
    const float* __restrict__ s4, const float* __restrict__ s5,
    unsigned short* __restrict__ d0, unsigned short* __restrict__ d1,
    unsigned short* __restrict__ d2, unsigned short* __restrict__ d3,
    unsigned short* __restrict__ d4, unsigned short* __restrict__ d5) {
  long i = (long)(blockIdx.x * 256 + threadIdx.x) * 8;
  const float* src; unsigned short* dst;
  if (i < 4194304)      { src = s0; dst = d0; }
  else if (i < 6291456) { src = s1; dst = d1; i -= 4194304; }
  else if (i < 6553600) { src = s2; dst = d2; i -= 6291456; }
  else if (i < 6815744) { src = s3; dst = d3; i -= 6553600; }
  else if (i < 6946816) { src = s4; dst = d4; i -= 6815744; }
  else                  { src = s5; dst = d5; i -= 6946816; }
  const float4 v0 = *(const float4*)&src[i];
  const float4 v1 = *(const float4*)&src[i + 4];
  bf16x8 o;
  o[0] = (short)f2bf(v0.x); o[1] = (short)f2bf(v0.y);
  o[2] = (short)f2bf(v0.z); o[3] = (short)f2bf(v0.w);
  o[4] = (short)f2bf(v1.x); o[5] = (short)f2bf(v1.y);
  o[6] = (short)f2bf(v1.z); o[7] = (short)f2bf(v1.w);
  *(bf16x8*)&dst[i] = o;
}

// ---------------- fused add + RMSNorm ----------------
__global__ __launch_bounds__(256) void addnorm_kernel(
    const float* __restrict__ hs, float* __restrict__ residual,
    const float* __restrict__ w, float* __restrict__ out,
    unsigned short* __restrict__ outb, int first) {
  const int row = blockIdx.x;
  const int t = threadIdx.x;
  const float* hp = hs + (long)row * DMODEL;
  float* rp = residual + (long)row * DMODEL;
  float r0 = hp[t], r1 = hp[t + 256];
  if (!first) { r0 += rp[t]; r1 += rp[t + 256]; }
  rp[t] = r0; rp[t + 256] = r1;
  float ss = r0 * r0 + r1 * r1;
  #pragma unroll
  for (int off = 32; off; off >>= 1) ss += __shfl_xor(ss, off, 64);
  __shared__ float sw[4];
  const int wid = t >> 6, lane = t & 63;
  if (lane == 0) sw[wid] = ss;
  __syncthreads();
  const float tot = sw[0] + sw[1] + sw[2] + sw[3];
  const float scale = rsqrtf(tot * (1.0f / (float)DMODEL) + EPSV);
  const float v0 = r0 * scale * w[t];
  const float v1 = r1 * scale * w[t + 256];
  if (out) {
    out[(long)row * DMODEL + t] = v0;
    out[(long)row * DMODEL + t + 256] = v1;
  }
  if (outb) {
    outb[(long)row * DMODEL + t] = f2bf(v0);
    outb[(long)row * DMODEL + t + 256] = f2bf(v1);
  }
}

#define LDK2 72

// ---------------- in_proj GEMM: 128M x 64N, BK=64, reg-prefetch -------------
__global__ __launch_bounds__(256) void gemm_in_kernel(
    const unsigned short* __restrict__ A, const unsigned short* __restrict__ B,
    float* __restrict__ C) {
  __shared__ unsigned short As[128 * LDK2];
  __shared__ unsigned short Bs[64 * LDK2];
  const int t = threadIdx.x;
  const int m0 = blockIdx.y * 128, n0 = blockIdx.x * 64;
  const int lane = t & 63;
  const int w = t >> 6;
  const int wr = (w >> 1) * 64, wc = (w & 1) * 32;
  const int fr = lane & 15;
  const int fq = lane >> 4;
  const int K = DMODEL;

  f32x4 acc[4][2];
  #pragma unroll
  for (int i = 0; i < 4; ++i)
    #pragma unroll
    for (int j = 0; j < 2; ++j) {
      f32x4 z = {0.f, 0.f, 0.f, 0.f};
      acc[i][j] = z;
    }

  const int arow = t >> 1, ako = (t & 1) * 32;   // A: 128 x 64
  const int brow = t >> 2, bko = (t & 3) * 16;   // B: 64 x 64

  bf16x8 pa[4], pb[2];
  #define LOADG_IN(k0_) do {                                              \
    const unsigned short* ap = &A[(long)(m0 + arow) * K + (k0_) + ako];   \
    pa[0] = *(const bf16x8*)ap;        pa[1] = *(const bf16x8*)(ap + 8);  \
    pa[2] = *(const bf16x8*)(ap + 16); pa[3] = *(const bf16x8*)(ap + 24); \
    const unsigned short* bp = &B[(long)(n0 + brow) * K + (k0_) + bko];   \
    pb[0] = *(const bf16x8*)bp;        pb[1] = *(const bf16x8*)(bp + 8);  \
  } while (0)

  LOADG_IN(0);
  for (int k0 = 0; k0 < K; k0 += 64) {
    if (k0) __syncthreads();
    *(bf16x8*)&As[arow * LDK2 + ako]      = pa[0];
    *(bf16x8*)&As[arow * LDK2 + ako + 8]  = pa[1];
    *(bf16x8*)&As[arow * LDK2 + ako + 16] = pa[2];
    *(bf16x8*)&As[arow * LDK2 + ako + 24] = pa[3];
    *(bf16x8*)&Bs[brow * LDK2 + bko]      = pb[0];
    *(bf16x8*)&Bs[brow * LDK2 + bko + 8]  = pb[1];
    __syncthreads();
    if (k0 + 64 < K) LOADG_IN(k0 + 64);
    #pragma unroll
    for (int h = 0; h < 2; ++h) {
      bf16x8 af[4], bg[2];
      #pragma unroll
      for (int i = 0; i < 4; ++i)
        af[i] = *(const bf16x8*)&As[(wr + i * 16 + fr) * LDK2 + h * 32 + fq * 8];
      #pragma unroll
      for (int j = 0; j < 2; ++j)
        bg[j] = *(const bf16x8*)&Bs[(wc + j * 16 + fr) * LDK2 + h * 32 + fq * 8];
      #pragma unroll
      for (int i = 0; i < 4; ++i)
        #pragma unroll
        for (int j = 0; j < 2; ++j)
          acc[i][j] = __builtin_amdgcn_mfma_f32_16x16x32_bf16(
              af[i], bg[j], acc[i][j], 0, 0, 0);
    }
  }
  #undef LOADG_IN

  #pragma unroll
  for (int i = 0; i < 4; ++i)
    #pragma unroll
    for (int j = 0; j < 2; ++j)
      #pragma unroll
      for (int r2 = 0; r2 < 4; ++r2) {
        const int m = m0 + wr + i * 16 + fq * 4 + r2;
        const int n = n0 + wc + j * 16 + fr;
        C[(long)m * NBL + n] = acc[i][j][r2];
      }
}

// ---------------- conv+SiLU -> transposed bf16 xcT only ----------------
__global__ __launch_bounds__(256) void conv_silu_kernel(
    const float* __restrict__ xz,
    const float* __restrict__ cw_f, const float* __restrict__ cb_f,
    const float* __restrict__ cw_r, const float* __restrict__ cb_r,
    unsigned short* __restrict__ xcT) {
  __shared__ unsigned short tile[32][33];
  const int dir = blockIdx.z;
  const int n0 = blockIdx.x * 32, d0 = blockIdx.y * 32;
  const int b = n0 >> 9;
  const int l0 = n0 & (SEQ - 1);
  const float* cw = dir ? cw_r : cw_f;
  const float* cb = dir ? cb_r : cb_f;
  unsigned short* dst = xcT + (long)dir * DINNER * NBL;
  const int t = threadIdx.x;
  const int c = t & 31, rr = t >> 5;
  #pragma unroll
  for (int p = 0; p < 4; ++p) {
    const int d = d0 + p * 8 + rr;
    const int l = l0 + c;
    const float* xi = xz + (long)d * NBL + b * SEQ;
    float sum = cb[d];
    #pragma unroll
    for (int k = 0; k < 4; ++k) {
      const int tt = l - 3 + k;
      if (tt >= 0) {
        const int src = dir ? (SEQ - 1 - tt) : tt;
        sum += cw[d * 4 + k] * xi[src];
      }
    }
    const float v = sum * sigmoidf_(sum);
    tile[p * 8 + rr][c] = f2bf(v);
  }
  __syncthreads();
  #pragma unroll
  for (int p = 0; p < 4; ++p) {
    const int n = n0 + p * 8 + rr;
    dst[(long)n * DINNER + d0 + c] = tile[c][p * 8 + rr];
  }
}

// ---------------- x_dbl via MFMA: 64M x 32N, BK=64, grid (32,2) -------------
// rows<32 -> dtT bf16 (dir,n,32); rows>=32 -> xbcT fp32 [slot][NBL].
__global__ __launch_bounds__(256) void xdbl_mfma_kernel(
    const unsigned short* __restrict__ xpwb_f, const unsigned short* __restrict__ xpwb_r,
    const unsigned short* __restrict__ xcT,
    unsigned short* __restrict__ dtT,
    float* __restrict__ xbc_f, float* __restrict__ xbc_r) {
  __shared__ unsigned short As[64 * LDK2];
  __shared__ unsigned short Bs[32 * LDK2];
  const int t = threadIdx.x;
  const int dir = blockIdx.y;
  const int n0 = blockIdx.x * 32;
  const unsigned short* A = dir ? xpwb_r : xpwb_f;
  const unsigned short* B = xcT + (long)dir * DINNER * NBL;
  float* xbc = dir ? xbc_r : xbc_f;
  unsigned short* dtt = dtT + (long)dir * NBL * DTRANK;

  const int lane = t & 63;
  const int w = t >> 6;
  const int wr = (w >> 1) * 32, wc = (w & 1) * 16;
  const int fr = lane & 15;
  const int fq = lane >> 4;

  f32x4 acc[2];
  #pragma unroll
  for (int i = 0; i < 2; ++i) {
    f32x4 z = {0.f, 0.f, 0.f, 0.f};
    acc[i] = z;
  }

  const int arow = t >> 2, ako = (t & 3) * 16;   // A: 64 x 64
  const int brow = t >> 3, bko = (t & 7) * 8;    // B: 32 x 64

  bf16x8 pa[2], pb;
  #define LOADG_XD(k0_) do {                                                   \
    const unsigned short* ap = &A[(long)arow * DINNER + (k0_) + ako];          \
    pa[0] = *(const bf16x8*)ap;        pa[1] = *(const bf16x8*)(ap + 8);       \
    pb = *(const bf16x8*)&B[(long)(n0 + brow) * DINNER + (k0_) + bko];         \
  } while (0)

  LOADG_XD(0);
  for (int k0 = 0; k0 < DINNER; k0 += 64) {
    if (k0) __syncthreads();
    *(bf16x8*)&As[arow * LDK2 + ako]     = pa[0];
    *(bf16x8*)&As[arow * LDK2 + ako + 8] = pa[1];
    *(bf16x8*)&Bs[brow * LDK2 + bko]     = pb;
    __syncthreads();
    if (k0 + 64 < DINNER) LOADG_XD(k0 + 64);
    #pragma unroll
    for (int h = 0; h < 2; ++h) {
      bf16x8 af[2], bg;
      #pragma unroll
      for (int i = 0; i < 2; ++i)
        af[i] = *(const bf16x8*)&As[(wr + i * 16 + fr) * LDK2 + h * 32 + fq * 8];
      bg = *(const bf16x8*)&Bs[(wc + fr) * LDK2 + h * 32 + fq * 8];
      #pragma unroll
      for (int i = 0; i < 2; ++i)
        acc[i] = __builtin_amdgcn_mfma_f32_16x16x32_bf16(af[i], bg, acc[i], 0, 0, 0);
    }
  }
  #undef LOADG_XD

  #pragma unroll
  for (int i = 0; i < 2; ++i)
    #pragma unroll
    for (int r2 = 0; r2 < 4; ++r2) {
      const int m = wr + i * 16 + fq * 4 + r2;
      const int n = n0 + wc + fr;
      const float v = acc[i][r2];
      if (m < DTRANK) dtt[(long)n * DTRANK + m] = f2bf(v);
      else xbc[(long)(m - 32) * NBL + n] = v;   // slot-major
    }
}

// ---------------- fused delta+conv+scan+gate+transpose, dir-split waves -----
// 512 blocks x 8 waves (512 thr); wave = one (b,d,dir); 4 d-rows per block.
// delta computed in-register from dtT/dtw (replaces deltam kernel).
static __device__ __forceinline__ void scan_pass(
    const float dt[8], const float u[8],
    const float* __restrict__ bct, const float* __restrict__ Alog,
    float Dv, int lane, float out[8]) {
  float dtu[8];
  #pragma unroll
  for (int j = 0; j < 8; ++j) { dtu[j] = dt[j] * u[j]; out[j] = 0.f; }

  for (int n = 0; n < DSTATE; ++n) {
    const float An = -__expf(Alog[n]);
    float Bv[8], Cv[8], dA[8], cB[8];
    {
      const float* bp = bct + (long)n * NBL;
      const float* cp = bct + (long)(DSTATE + n) * NBL;
      const float4 b0 = *(const float4*)&bp[0];
      const float4 b1 = *(const float4*)&bp[4];
      Bv[0] = b0.x; Bv[1] = b0.y; Bv[2] = b0.z; Bv[3] = b0.w;
      Bv[4] = b1.x; Bv[5] = b1.y; Bv[6] = b1.z; Bv[7] = b1.w;
      const float4 c0 = *(const float4*)&cp[0];
      const float4 c1 = *(const float4*)&cp[4];
      Cv[0] = c0.x; Cv[1] = c0.y; Cv[2] = c0.z; Cv[3] = c0.w;
      Cv[4] = c1.x; Cv[5] = c1.y; Cv[6] = c1.z; Cv[7] = c1.w;
    }
    float h = 0.f, P = 1.f;
    #pragma unroll
    for (int j = 0; j < 8; ++j) {
      dA[j] = __expf(dt[j] * An);
      cB[j] = dtu[j] * Bv[j];
      h = fmaf(h, dA[j], cB[j]);
      P *= dA[j];
    }
    float hs = h, Ps = P;
    #pragma unroll
    for (int off = 1; off < 64; off <<= 1) {
      const float hp = __shfl_up(hs, off, 64);
      const float Pp = __shfl_up(Ps, off, 64);
      if (lane >= off) { hs = fmaf(hp, Ps, hs); Ps *= Pp; }
    }
    float h0 = __shfl_up(hs, 1, 64);
    if (lane == 0) h0 = 0.f;
    #pragma unroll
    for (int j = 0; j < 8; ++j) {
      h0 = fmaf(h0, dA[j], cB[j]);
      out[j] = fmaf(h0, Cv[j], out[j]);
    }
  }
  #pragma unroll
  for (int j = 0; j < 8; ++j) out[j] = fmaf(Dv, u[j], out[j]);
}

__global__ __launch_bounds__(512) void scan_split_kernel(
    const unsigned short* __restrict__ dtT,
    const unsigned short* __restrict__ dtwb_f, const unsigned short* __restrict__ dtwb_r,
    const float* __restrict__ dtb_f, const float* __restrict__ dtb_r,
    const float* __restrict__ xbc_f, const float* __restrict__ xbc_r,
    const float* __restrict__ Alog_f, const float* __restrict__ Alog_r,
    const float* __restrict__ Dsk_f, const float* __restrict__ Dsk_r,
    const float* __restrict__ cw_f, const float* __restrict__ cb_f,
    const float* __restrict__ cw_r, const float* __restrict__ cb_r,
    const float* __restrict__ xz, unsigned short* __restrict__ ybt) {
  __shared__ float s_r[4][2][256];
  __shared__ unsigned short s_y[4][512];
  const int t = threadIdx.x;           // 0..511
  const int wv = t >> 6;               // 0..7
  const int lane = t & 63;
  const int dir = wv & 1;
  const int dl = wv >> 1;              // local d 0..3
  const int row = blockIdx.x * 4 + dl;
  const int b = row >> 10, d = row & 1023;
  const long rbase = (long)d * NBL + b * SEQ;

  // ---- load x row ----
  float xv[8];
  {
    const float* xp = xz + rbase + lane * 8;
    const float4 a0 = *(const float4*)&xp[0];
    const float4 a1 = *(const float4*)&xp[4];
    xv[0] = a0.x; xv[1] = a0.y; xv[2] = a0.z; xv[3] = a0.w;
    xv[4] = a1.x; xv[5] = a1.y; xv[6] = a1.z; xv[7] = a1.w;
  }
  if (dir) {
    float xr[8];
    #pragma unroll
    for (int j = 0; j < 8; ++j) xr[j] = __shfl(xv[7 - j], 63 - lane, 64);
    #pragma unroll
    for (int j = 0; j < 8; ++j) xv[j] = xr[j];
  }
  // ---- conv + silu (this dir) ----
  const float* cwp = dir ? cw_r : cw_f;
  const float* cbp = dir ? cb_r : cb_f;
  float u[8];
  {
    const float cw0 = cwp[d * 4], cw1 = cwp[d * 4 + 1], cw2 = cwp[d * 4 + 2],
                cw3 = cwp[d * 4 + 3], cb = cbp[d];
    const float xm1 = __shfl_up(xv[7], 1, 64);
    const float xm2 = __shfl_up(xv[6], 1, 64);
    const float xm3 = __shfl_up(xv[5], 1, 64);
    const float ext[3] = {xm3, xm2, xm1};
    #pragma unroll
    for (int j = 0; j < 8; ++j) {
      float s = cb + cw3 * xv[j];
      const int p = lane * 8 + j;
      #pragma unroll
      for (int k = 0; k < 3; ++k) {
        const int idx = j - 3 + k;
        const float xval = (idx >= 0) ? xv[idx] : ext[3 + idx];
        if (p - 3 + k >= 0) s += (k == 0 ? cw0 : (k == 1 ? cw1 : cw2)) * xval;
      }
      u[j] = s * sigmoidf_(s);
    }
  }

  // ---- delta = softplus(dtw[d] . dtT[n] + dtb[d]) in-register ----
  float dtv[8];
  {
    const unsigned short* dw = ((dir ? dtwb_r : dtwb_f)) + (long)d * DTRANK;
    float w32[32];
    #pragma unroll
    for (int q = 0; q < 4; ++q) {
      const bf16x8 v = *(const bf16x8*)&dw[q * 8];
      #pragma unroll
      for (int e = 0; e < 8; ++e) w32[q * 8 + e] = bf2f(v[e]);
    }
    const float bias = (dir ? dtb_r : dtb_f)[d];
    const unsigned short* dtrow =
        dtT + (long)dir * NBL * DTRANK + ((long)b * SEQ + lane * 8) * DTRANK;
    #pragma unroll
    for (int j = 0; j < 8; ++j) {
      const bf16x8* rp = (const bf16x8*)&dtrow[(long)j * DTRANK];
      float acc = bias;
      #pragma unroll
      for (int q = 0; q < 4; ++q) {
        const bf16x8 rv = rp[q];
        #pragma unroll
        for (int e = 0; e < 8; ++e)
          acc = fmaf(w32[q * 8 + e], bf2f(rv[e]), acc);
      }
      dtv[j] = softplusf_(acc);
    }
  }

  float a[8];
  scan_pass(dtv, u,
            (dir ? xbc_r : xbc_f) + b * SEQ + lane * 8,
            (dir ? Alog_r : Alog_f) + d * DSTATE,
            (dir ? Dsk_r : Dsk_f)[d], lane, a);

  if (dir) {
    // mirror into forward order and park (two conflict-free float4 planes)
    float fv[8];
    #pragma unroll
    for (int j = 0; j < 8; ++j) fv[j] = __shfl(a[7 - j], 63 - lane, 64);
    float4 q0 = {fv[0], fv[1], fv[2], fv[3]};
    float4 q1 = {fv[4], fv[5], fv[6], fv[7]};
    *(float4*)&s_r[dl][0][lane * 4] = q0;
    *(float4*)&s_r[dl][1][lane * 4] = q1;
  }
  __syncthreads();
  if (!dir) {
    const float* zp = xz + (long)(DINNER + d) * NBL + b * SEQ + lane * 8;
    const float4 z0 = *(const float4*)&zp[0];
    const float4 z1 = *(const float4*)&zp[4];
    const float zv[8] = {z0.x, z0.y, z0.z, z0.w, z1.x, z1.y, z1.z, z1.w};
    const float4 r0 = *(const float4*)&s_r[dl][0][lane * 4];
    const float4 r1 = *(const float4*)&s_r[dl][1][lane * 4];
    const float rr[8] = {r0.x, r0.y, r0.z, r0.w, r1.x, r1.y, r1.z, r1.w};
    bf16x8 ob;
    #pragma unroll
    for (int j = 0; j < 8; ++j) {
      const float tot = a[j] + rr[j];
      ob[j] = (short)f2bf(tot * (zv[j] * sigmoidf_(zv[j])));
    }
    *(bf16x8*)&s_y[dl][lane * 8] = ob;
  }
  __syncthreads();
  // ---- block gathers ushort4 into ybt (n, e) ----
  const int d0 = (blockIdx.x * 4) & 1023;
  const int bb = (blockIdx.x * 4) >> 10;
  unsigned short* yrow = ybt + (long)(bb * SEQ) * DINNER + d0;
  {
    const int n = t;  // 0..511
    ushort4 v = {s_y[0][n], s_y[1][n], s_y[2][n], s_y[3][n]};
    *(ushort4*)&yrow[(long)n * DINNER] = v;
  }
}

// ---------------- out_proj GEMM: 64x64 tile, grid (16,8), BK=64 -------------
__global__ __launch_bounds__(256) void gemm_out_kernel(
    const unsigned short* __restrict__ A, const unsigned short* __restrict__ B,
    float* __restrict__ C) {
  __shared__ unsigned short As[64 * LDK2];
  __shared__ unsigned short Bs[64 * LDK2];
  const int t = threadIdx.x;
  const int m0 = blockIdx.y * 64, n0 = blockIdx.x * 64;
  const int lane = t & 63;
  const int w = t >> 6;
  const int wr = (w >> 1) * 32, wc = (w & 1) * 32;
  const int fr = lane & 15;
  const int fq = lane >> 4;
  const int K = DINNER;

  f32x4 acc[2][2];
  #pragma unroll
  for (int i = 0; i < 2; ++i)
    #pragma unroll
    for (int j = 0; j < 2; ++j) {
      f32x4 z = {0.f, 0.f, 0.f, 0.f};
      acc[i][j] = z;
    }

  const int arow = t >> 2, ako = (t & 3) * 16;   // 64 x 64 each

  bf16x8 pa[2], pb[2];
  #define LOADG_OUT(k0_) do {                                              \
    const unsigned short* ap = &A[(long)(m0 + arow) * K + (k0_) + ako];    \
    pa[0] = *(const bf16x8*)ap;        pa[1] = *(const bf16x8*)(ap + 8);   \
    const unsigned short* bp = &B[(long)(n0 + arow) * K + (k0_) + ako];    \
    pb[0] = *(const bf16x8*)bp;        pb[1] = *(const bf16x8*)(bp + 8);   \
  } while (0)

  LOADG_OUT(0);
  for (int k0 = 0; k0 < K; k0 += 64) {
    if (k0) __syncthreads();
    *(bf16x8*)&As[arow * LDK2 + ako]     = pa[0];
    *(bf16x8*)&As[arow * LDK2 + ako + 8] = pa[1];
    *(bf16x8*)&Bs[arow * LDK2 + ako]     = pb[0];
    *(bf16x8*)&Bs[arow * LDK2 + ako + 8] = pb[1];
    __syncthreads();
    if (k0 + 64 < K) LOADG_OUT(k0 + 64);
    #pragma unroll
    for (int h = 0; h < 2; ++h) {
      bf16x8 af[2], bg[2];
      #pragma unroll
      for (int i = 0; i < 2; ++i) {
        af[i] = *(const bf16x8*)&As[(wr + i * 16 + fr) * LDK2 + h * 32 + fq * 8];
        bg[i] = *(const bf16x8*)&Bs[(wc + i * 16 + fr) * LDK2 + h * 32 + fq * 8];
      }
      #pragma unroll
      for (int i = 0; i < 2; ++i)
        #pragma unroll
        for (int j = 0; j < 2; ++j)
          acc[i][j] = __builtin_amdgcn_mfma_f32_16x16x32_bf16(
              af[i], bg[j], acc[i][j], 0, 0, 0);
    }
  }
  #undef LOADG_OUT

  #pragma unroll
  for (int i = 0; i < 2; ++i)
    #pragma unroll
    for (int j = 0; j < 2; ++j)
      #pragma unroll
      for (int r2 = 0; r2 < 4; ++r2) {
        const int m = m0 + wr + i * 16 + fq * 4 + r2;
        const int n = n0 + wc + j * 16 + fr;
        C[(long)n * DMODEL + m] = acc[i][j][r2];
      }
}

extern "C" void kernel_launch(void* const* d_in, const int* in_sizes, int n_in,
                              void* d_out, int out_size, void* d_ws, size_t ws_size,
                              hipStream_t stream) {
  (void)in_sizes; (void)n_in; (void)out_size; (void)ws_size;
  const float* x       = (const float*)d_in[0];
  const float* norm_w  = (const float*)d_in[1];
  const float* in_proj = (const float*)d_in[2];
  const float* convw_f = (const float*)d_in[3];
  const float* convb_f = (const float*)d_in[4];
  const float* xpw_f   = (const float*)d_in[5];
  const float* dtw_f   = (const float*)d_in[6];
  const float* dtb_f   = (const float*)d_in[7];
  const float* Alog_f  = (const float*)d_in[8];
  const float* Dsk_f   = (const float*)d_in[9];
  const float* convw_r = (const float*)d_in[10];
  const float* convb_r = (const float*)d_in[11];
  const float* xpw_r   = (const float*)d_in[12];
  const float* dtw_r   = (const float*)d_in[13];
  const float* dtb_r   = (const float*)d_in[14];
  const float* Alog_r  = (const float*)d_in[15];
  const float* Dsk_r   = (const float*)d_in[16];
  const float* out_w   = (const float*)d_in[17];
  const float* normf_w = (const float*)d_in[18];

  float* ws = (float*)d_ws;
  float* residual = ws;  ws += 524288;
  float* xzbuf    = ws;  ws += 2097152;
  float* xbc_f    = ws;  ws += 32768;
  float* xbc_r    = ws;  ws += 32768;
  float* hnb_f    = ws;  ws += 262144;   // 1024x512 bf16
  float* wbfin_f  = ws;  ws += 2097152;  // 4x2048x512 bf16
  float* wbfout_f = ws;  ws += 1048576;  // 4x512x1024 bf16
  float* ybt_f    = ws;  ws += 524288;   // 1024x1024 bf16
  float* xcT_f    = ws;  ws += 1048576;  // 2 x 1024 x 1024 bf16
  float* dtT_f    = ws;  ws += 32768;    // 2 x 1024 x 32 bf16
  float* xpwb_f_  = ws;  ws += 131072;
  float* xpwb_r_  = ws;  ws += 131072;
  float* dtwb_f_  = ws;  ws += 65536;
  float* dtwb_r_  = ws;  ws += 65536;

  unsigned short* hnb = (unsigned short*)hnb_f;
  unsigned short* wbfin = (unsigned short*)wbfin_f;
  unsigned short* wbfout = (unsigned short*)wbfout_f;
  unsigned short* ybt = (unsigned short*)ybt_f;
  unsigned short* xcT = (unsigned short*)xcT_f;
  unsigned short* dtT = (unsigned short*)dtT_f;
  unsigned short* xpwb_f = (unsigned short*)xpwb_f_;
  unsigned short* xpwb_r = (unsigned short*)xpwb_r_;
  unsigned short* dtwb_f = (unsigned short*)dtwb_f_;
  unsigned short* dtwb_r = (unsigned short*)dtwb_r_;

  float* outp = (float*)d_out;

  wconvert_kernel<<<3456, 256, 0, stream>>>(
      in_proj, out_w, xpw_f, xpw_r, dtw_f, dtw_r,
      wbfin, wbfout, xpwb_f, xpwb_r, dtwb_f, dtwb_r);

  for (int layer = 0; layer < 4; ++layer) {
    const float* hsrc = layer == 0 ? x : (outp + (long)layer * 524288);
    addnorm_kernel<<<1024, 256, 0, stream>>>(
        hsrc, residual, norm_w + layer * DMODEL, nullptr, hnb, layer == 0 ? 1 : 0);
    gemm_in_kernel<<<dim3(16, 16), 256, 0, stream>>>(
        wbfin + (long)layer * 2048 * 512, hnb, xzbuf);
    conv_silu_kernel<<<dim3(32, 32, 2), 256, 0, stream>>>(
        xzbuf, convw_f + layer * DINNER * 4, convb_f + layer * DINNER,
        convw_r + layer * DINNER * 4, convb_r + layer * DINNER, xcT);
    xdbl_mfma_kernel<<<dim3(32, 2), 256, 0, stream>>>(
        xpwb_f + (long)layer * 64 * DINNER, xpwb_r + (long)layer * 64 * DINNER,
        xcT, dtT, xbc_f, xbc_r);
    scan_split_kernel<<<512, 512, 0, stream>>>(
        dtT, dtwb_f + (long)layer * DINNER * DTRANK,
        dtwb_r + (long)layer * DINNER * DTRANK,
        dtb_f + layer * DINNER, dtb_r + layer * DINNER,
        xbc_f, xbc_r,
        Alog_f + layer * DINNER * DSTATE, Alog_r + layer * DINNER * DSTATE,
        Dsk_f + layer * DINNER, Dsk_r + layer * DINNER,
        convw_f + layer * DINNER * 4, convb_f + layer * DINNER,
        convw_r + layer * DINNER * 4, convb_r + layer * DINNER,
        xzbuf, ybt);
    gemm_out_kernel<<<dim3(16, 8), 256, 0, stream>>>(
        wbfout + (long)layer * 512 * 1024, ybt,
        outp + (long)(1 + layer) * 524288);
  }
  addnorm_kernel<<<1024, 256, 0, stream>>>(
      outp + 4 * 524288, residual, normf_w, outp, nullptr, 0);
}